// Round 1
// baseline (2886.693 us; speedup 1.0000x reference)
//
#include <hip/hip_runtime.h>
#include <math.h>

#define T_SEQ 256
#define C_DIM 512
#define D_DIM 1024
#define BN_TOT 320
#define NHEAD 4
#define DHEAD 128
#define QKV_N 1536
#define EPS 1e-5f
#define ATT_SCALE 0.08838834764831845f

typedef unsigned short u16;
typedef unsigned int u32;
typedef __attribute__((ext_vector_type(8))) short bf16x8;
typedef __attribute__((ext_vector_type(4))) float f32x4;

__device__ __forceinline__ u16 f2bf(float f) {
  union { float f; u32 u; } v; v.f = f;
  u32 r = v.u + 0x7fffu + ((v.u >> 16) & 1u);
  return (u16)(r >> 16);
}

__device__ __forceinline__ void gload_lds16(const u16* g, u16* l) {
  __builtin_amdgcn_global_load_lds((const __attribute__((address_space(1))) u32*)g,
                                   (__attribute__((address_space(3))) u32*)l, 16, 0, 0);
}

// ---------------- prep kernels -------------------------------------------------------
// 4 elems/thread: float4 in, ushort4 out (G13 vectorization)
__global__ void convert_x(const float* __restrict__ x, u16* __restrict__ xpad) {
  size_t i4 = ((size_t)blockIdx.x * 256 + threadIdx.x) * 4;
  if (i4 >= (size_t)BN_TOT * 258 * 1024) return;
  size_t row = i4 >> 10; int col = (int)(i4 & 1023);
  int bn = (int)(row / 258), tr = (int)(row % 258);
  ushort4 o;
  if (tr == 0 || tr == 257) {
    o.x = 0; o.y = 0; o.z = 0; o.w = 0;
  } else {
    float4 v = *(const float4*)&x[((size_t)bn * 256 + tr - 1) * 1024 + col];
    o.x = f2bf(v.x); o.y = f2bf(v.y); o.z = f2bf(v.z); o.w = f2bf(v.w);
  }
  *(ushort4*)&xpad[i4] = o;
}

__global__ void prep_wct(const float* __restrict__ Wemb, u16* __restrict__ Wct) {
  int idx = blockIdx.x * 256 + threadIdx.x;
  if (idx >= 3 * C_DIM * D_DIM) return;
  int d = idx & 1023;
  int c = (idx >> 10) & 511;
  int s = idx >> 19;
  Wct[idx] = f2bf(Wemb[(c * D_DIM + d) * 3 + s]);
}

// tiled transpose: src [K][N] fp32 -> dst [N][K] bf16. 32x32 tiles, coalesced both sides.
__launch_bounds__(256)
__global__ void transpose_w(const float* __restrict__ src, u16* __restrict__ dst, int K, int N) {
  __shared__ float t[32][33];
  int tid = threadIdx.x;
  int n0 = blockIdx.x * 32, k0 = blockIdx.y * 32;
  int r = tid >> 3, c4 = (tid & 7) * 4;
  float4 v = *(const float4*)&src[(size_t)(k0 + r) * N + n0 + c4];
  t[r][c4 + 0] = v.x; t[r][c4 + 1] = v.y; t[r][c4 + 2] = v.z; t[r][c4 + 3] = v.w;
  __syncthreads();
  ushort4 o;
  o.x = f2bf(t[c4 + 0][r]);
  o.y = f2bf(t[c4 + 1][r]);
  o.z = f2bf(t[c4 + 2][r]);
  o.w = f2bf(t[c4 + 3][r]);
  *(ushort4*)&dst[(size_t)(n0 + r) * K + k0 + c4] = o;
}

__global__ void prep_c1t(const float* __restrict__ c1W, float* __restrict__ Wt) {
  int idx = blockIdx.x * 256 + threadIdx.x;
  if (idx >= C_DIM * 32) return;
  int n = idx & 31;
  int k = idx >> 5;
  Wt[idx] = c1W[n * C_DIM + k];
}

// ---------------- bf16 MFMA GEMM -----------------------------------------------------
// EPI: 0 = store fp32, 1 = C += acc+bias (fp32), 2 = Cbf = bf16(gelu(acc+bias)),
//      3 = C = relu(acc+bias) fp32, 4 = Cbf = bf16(acc)
template <int S, int EPI>
__launch_bounds__(256)
__global__ void gemm_mfma(const u16* __restrict__ A, int lda, int aRowsPerZ,
                          const u16* __restrict__ Bt, size_t bShift, int K,
                          float* __restrict__ C, u16* __restrict__ Cbf,
                          const float* __restrict__ bias, int N, int cRowsPerZ) {
  __shared__ u16 lds[16384];
  u16* Alds = lds;
  u16* Blds = lds + 8192;

  const int tid = threadIdx.x;
  const int lane = tid & 63;
  const int wave = tid >> 6;
  const int wm = wave >> 1, wn = wave & 1;
  const int quad = lane >> 4;
  const int l15 = lane & 15;
  const int srow = lane >> 3;
  const int scol = (lane & 7) * 8;

  // T1: XCD-aware bijective chunked swizzle (nwg % 8 == 0 for all our launches).
  // HW round-robins consecutive dispatch ids across the 8 XCDs; this remap makes
  // each XCD own a CONTIGUOUS chunk of the (x-fastest) linear grid, so the nx
  // blocks sharing an A-panel land on one XCD's L2.
  unsigned gx = gridDim.x, gy = gridDim.y, gz = gridDim.z;
  unsigned orig = (blockIdx.z * gy + blockIdx.y) * gx + blockIdx.x;
  unsigned nwg = gx * gy * gz;
  unsigned wg = orig;
  if ((nwg & 7u) == 0u) wg = (orig & 7u) * (nwg >> 3) + (orig >> 3);
  unsigned bx = wg % gx;
  unsigned tmp = wg / gx;
  unsigned by = tmp % gy;
  unsigned bz = tmp / gy;

  const int n0 = bx * 128;
  const int arow0 = bz * aRowsPerZ + by * 128;
  const int crow0 = bz * cRowsPerZ + by * 128;

  f32x4 acc[4][4] = {};

  for (int s = 0; s < S; ++s) {
    const u16* Ab = A + ((size_t)arow0 + s) * (size_t)lda;
    const u16* Bb = Bt + (size_t)s * bShift;
    for (int k0 = 0; k0 < K; k0 += 64) {
#pragma unroll
      for (int c = 0; c < 4; ++c) {
        int chunk = wave * 4 + c;
        gload_lds16(Ab + (size_t)(chunk * 8 + srow) * lda + k0 + scol,
                    Alds + chunk * 512);
      }
#pragma unroll
      for (int c = 0; c < 4; ++c) {
        int chunk = wave * 4 + c;
        gload_lds16(Bb + (size_t)(n0 + chunk * 8 + srow) * K + k0 + scol,
                    Blds + chunk * 512);
      }
      __syncthreads();
#pragma unroll
      for (int kk = 0; kk < 64; kk += 32) {
        bf16x8 af[4], bfr[4];
#pragma unroll
        for (int mt = 0; mt < 4; ++mt)
          af[mt] = *(const bf16x8*)&Alds[(wm * 64 + mt * 16 + l15) * 64 + kk + quad * 8];
#pragma unroll
        for (int nt = 0; nt < 4; ++nt)
          bfr[nt] = *(const bf16x8*)&Blds[(wn * 64 + nt * 16 + l15) * 64 + kk + quad * 8];
#pragma unroll
        for (int mt = 0; mt < 4; ++mt)
#pragma unroll
          for (int nt = 0; nt < 4; ++nt)
            acc[mt][nt] = __builtin_amdgcn_mfma_f32_16x16x32_bf16(af[mt], bfr[nt], acc[mt][nt], 0, 0, 0);
      }
      __syncthreads();
    }
  }

#pragma unroll
  for (int mt = 0; mt < 4; ++mt) {
#pragma unroll
    for (int nt = 0; nt < 4; ++nt) {
      int col = n0 + wn * 64 + nt * 16 + l15;
      float bv = 0.f;
      if constexpr (EPI == 1 || EPI == 2 || EPI == 3) bv = bias[col];
#pragma unroll
      for (int r = 0; r < 4; ++r) {
        size_t row = (size_t)crow0 + wm * 64 + mt * 16 + quad * 4 + r;
        float v = acc[mt][nt][r];
        if constexpr (EPI == 0) {
          C[row * N + col] = v;
        } else if constexpr (EPI == 1) {
          C[row * N + col] += v + bv;
        } else if constexpr (EPI == 2) {
          float t = v + bv;
          Cbf[row * N + col] = f2bf(t * 0.5f * (1.f + erff(t * 0.70710678118f)));
        } else if constexpr (EPI == 3) {
          C[row * N + col] = fmaxf(v + bv, 0.f);
        } else {
          Cbf[row * N + col] = f2bf(v);
        }
      }
    }
  }
}

// ---------------- small fp32 GEMM (head c1: N=32) ------------------------------------
template <int NT, int EPI>
__launch_bounds__(256)
__global__ void gemm_f32(const float* __restrict__ A, const float* __restrict__ B,
                         float* __restrict__ C, const float* __restrict__ bias,
                         int M, int N, int K) {
  __shared__ __align__(16) float As[16][68];
  __shared__ __align__(16) float Bs[16][NT + 4];
  int tid = threadIdx.x;
  int tx = tid & 15, ty = tid >> 4;
  int n0 = blockIdx.x * NT, m0 = blockIdx.y * 64;
  constexpr int TN = NT / 16;
  float acc[4][TN] = {};
  int arow = tid >> 2, akg = (tid & 3) * 4;
  int bk, bng;
  if (NT == 64) { bk = tid >> 4; bng = (tid & 15) * 4; }
  else          { bk = tid >> 3; bng = (tid & 7) * 4; }
  bool bload = (NT == 64) || (tid < 128);
  const float* Ap = A + (size_t)(m0 + arow) * K + akg;
  const float* Bp = B + (size_t)bk * N + n0 + bng;
  for (int k0 = 0; k0 < K; k0 += 16) {
    float4 av = *(const float4*)(Ap + k0);
    float4 bv = make_float4(0.f, 0.f, 0.f, 0.f);
    if (bload) bv = *(const float4*)(Bp + (size_t)k0 * N);
    __syncthreads();
    As[akg + 0][arow] = av.x; As[akg + 1][arow] = av.y;
    As[akg + 2][arow] = av.z; As[akg + 3][arow] = av.w;
    if (bload) *(float4*)&Bs[bk][bng] = bv;
    __syncthreads();
#pragma unroll
    for (int k = 0; k < 16; ++k) {
      float4 a4 = *(const float4*)&As[k][ty * 4];
      float a[4] = {a4.x, a4.y, a4.z, a4.w};
      float b[TN];
#pragma unroll
      for (int j = 0; j < TN; j++) b[j] = Bs[k][tx * TN + j];
#pragma unroll
      for (int i = 0; i < 4; i++)
#pragma unroll
        for (int j = 0; j < TN; j++) acc[i][j] = fmaf(a[i], b[j], acc[i][j]);
    }
  }
#pragma unroll
  for (int i = 0; i < 4; i++) {
    size_t row = m0 + ty * 4 + i;
    float* Cp = C + row * (size_t)N + n0 + tx * TN;
#pragma unroll
    for (int j = 0; j < TN; j++) {
      float v = acc[i][j];
      if (EPI >= 1) v += bias[n0 + tx * TN + j];
      Cp[j] = v;
    }
  }
}

// ---------------- LayerNorm over last dim (512), bf16 out ----------------------------
// wave-per-row: float4 loads, pure shfl_xor reduce, ushort4 stores. 4 rows / block.
__launch_bounds__(256)
__global__ void ln_kernel(const float* __restrict__ h, const float* __restrict__ g,
                          const float* __restrict__ b, u16* __restrict__ u) {
  int row = blockIdx.x * 4 + (threadIdx.x >> 6);
  int lane = threadIdx.x & 63;
  const float* hp = h + (size_t)row * C_DIM + lane * 8;
  float4 a0 = *(const float4*)hp;
  float4 a1 = *(const float4*)(hp + 4);
  float s = a0.x + a0.y + a0.z + a0.w + a1.x + a1.y + a1.z + a1.w;
#pragma unroll
  for (int o = 32; o > 0; o >>= 1) s += __shfl_xor(s, o);
  float mu = s * (1.f / 512.f);
  float d[8] = {a0.x - mu, a0.y - mu, a0.z - mu, a0.w - mu,
                a1.x - mu, a1.y - mu, a1.z - mu, a1.w - mu};
  float q = 0.f;
#pragma unroll
  for (int j = 0; j < 8; ++j) q += d[j] * d[j];
#pragma unroll
  for (int o = 32; o > 0; o >>= 1) q += __shfl_xor(q, o);
  float rs = rsqrtf(q * (1.f / 512.f) + EPS);
  const float* gp = g + lane * 8;
  const float* bp = b + lane * 8;
  float4 g0 = *(const float4*)gp, g1 = *(const float4*)(gp + 4);
  float4 b0 = *(const float4*)bp, b1 = *(const float4*)(bp + 4);
  float gv[8] = {g0.x, g0.y, g0.z, g0.w, g1.x, g1.y, g1.z, g1.w};
  float bv[8] = {b0.x, b0.y, b0.z, b0.w, b1.x, b1.y, b1.z, b1.w};
  ushort4 o0, o1;
  o0.x = f2bf(d[0] * rs * gv[0] + bv[0]);
  o0.y = f2bf(d[1] * rs * gv[1] + bv[1]);
  o0.z = f2bf(d[2] * rs * gv[2] + bv[2]);
  o0.w = f2bf(d[3] * rs * gv[3] + bv[3]);
  o1.x = f2bf(d[4] * rs * gv[4] + bv[4]);
  o1.y = f2bf(d[5] * rs * gv[5] + bv[5]);
  o1.z = f2bf(d[6] * rs * gv[6] + bv[6]);
  o1.w = f2bf(d[7] * rs * gv[7] + bv[7]);
  u16* up = u + (size_t)row * C_DIM + lane * 8;
  *(ushort4*)up = o0;
  *(ushort4*)(up + 4) = o1;
}

// ---------------- MFMA flash attention: block = (head, bn), 8 waves ------------------
// qkv bf16 [bn][t][1536]; out bf16 [bn][t][512] at col hh*128.
__launch_bounds__(512, 2)
__global__ void attn_mfma(const u16* __restrict__ qkv, u16* __restrict__ o) {
  __shared__ u16 Ks[64 * 136];        // [kk][d], pad 136
  __shared__ u32 Vt32[128 * 44];      // [d][kk-pair], pad 44 dwords (=88 u16)
  __shared__ u16 Ps[8][32 * 80];      // per-wave P [m][kk], pad 80

  const int tid = threadIdx.x;
  const int lane = tid & 63, wave = tid >> 6;
  const int quad = lane >> 4, l15 = lane & 15;
  const int hh = blockIdx.x, bl = blockIdx.y;
  const u16* base = qkv + (size_t)bl * T_SEQ * QKV_N;

  // Q fragments in registers: rows wave*32 + mi*16 + l15
  bf16x8 qf[2][4];
#pragma unroll
  for (int mi = 0; mi < 2; mi++) {
    int row = wave * 32 + mi * 16 + l15;
    const u16* qp = base + (size_t)row * QKV_N + hh * DHEAD + quad * 8;
#pragma unroll
    for (int k0 = 0; k0 < 4; k0++)
      qf[mi][k0] = *(const bf16x8*)(qp + k0 * 32);
  }

  f32x4 oa[2][8] = {};
  float mrow[2][4], lrow[2][4];
#pragma unroll
  for (int mi = 0; mi < 2; mi++)
#pragma unroll
    for (int r = 0; r < 4; r++) { mrow[mi][r] = -1e30f; lrow[mi][r] = 0.f; }

  for (int kt = 0; kt < 4; kt++) {
    __syncthreads();
    // K tile 64x128 -> Ks (16 elems / thread)
    {
      int kk = tid >> 3, dbase = (tid & 7) * 16;
      const u16* kp = base + (size_t)(kt * 64 + kk) * QKV_N + C_DIM + hh * DHEAD + dbase;
      uint4 a = *(const uint4*)kp;
      uint4 b = *(const uint4*)(kp + 8);
      *(uint4*)&Ks[kk * 136 + dbase] = a;
      *(uint4*)&Ks[kk * 136 + dbase + 8] = b;
    }
    // V tile 64x128 -> Vt32 transposed (pairs of kk packed in u32)
    {
      int kkp = tid >> 4, dbase = (tid & 15) * 8;
      const u16* vp = base + (size_t)(kt * 64 + kkp * 2) * QKV_N + 2 * C_DIM + hh * DHEAD + dbase;
      union { uint4 u; u16 h[8]; } va, vb;
      va.u = *(const uint4*)vp;
      vb.u = *(const uint4*)(vp + QKV_N);
#pragma unroll
      for (int j = 0; j < 8; j++)
        Vt32[(dbase + j) * 44 + kkp] = (u32)va.h[j] | ((u32)vb.h[j] << 16);
    }
    __syncthreads();

    // S = Q @ K^T (raw, scaled later)
    f32x4 sa[2][4] = {};
#pragma unroll
    for (int k0 = 0; k0 < 4; k0++) {
      bf16x8 kf[4];
#pragma unroll
      for (int ni = 0; ni < 4; ni++)
        kf[ni] = *(const bf16x8*)&Ks[(ni * 16 + l15) * 136 + k0 * 32 + quad * 8];
      __builtin_amdgcn_s_setprio(1);
#pragma unroll
      for (int mi = 0; mi < 2; mi++)
#pragma unroll
        for (int ni = 0; ni < 4; ni++)
          sa[mi][ni] = __builtin_amdgcn_mfma_f32_16x16x32_bf16(qf[mi][k0], kf[ni], sa[mi][ni], 0, 0, 0);
      __builtin_amdgcn_s_setprio(0);
    }

    // online softmax (rows = quad*4+r within 16-tile; 16 lanes l15 share a row)
#pragma unroll
    for (int mi = 0; mi < 2; mi++) {
#pragma unroll
      for (int r = 0; r < 4; r++) {
        float mx = fmaxf(fmaxf(sa[mi][0][r], sa[mi][1][r]), fmaxf(sa[mi][2][r], sa[mi][3][r]));
        mx = fmaxf(mx, __shfl_xor(mx, 1));
        mx = fmaxf(mx, __shfl_xor(mx, 2));
        mx = fmaxf(mx, __shfl_xor(mx, 4));
        mx = fmaxf(mx, __shfl_xor(mx, 8));
        mx *= ATT_SCALE;
        float mnew = fmaxf(mrow[mi][r], mx);
        float alpha = __expf(mrow[mi][r] - mnew);
        mrow[mi][r] = mnew;
        float rs = 0.f;
#pragma unroll
        for (int ni = 0; ni < 4; ni++) {
          float p = __expf(sa[mi][ni][r] * ATT_SCALE - mnew);
          rs += p;
          Ps[wave][(mi * 16 + quad * 4 + r) * 80 + ni * 16 + l15] = f2bf(p);
        }
        rs += __shfl_xor(rs, 1);
        rs += __shfl_xor(rs, 2);
        rs += __shfl_xor(rs, 4);
        rs += __shfl_xor(rs, 8);
        lrow[mi][r] = lrow[mi][r] * alpha + rs;
#pragma unroll
        for (int nj = 0; nj < 8; nj++) oa[mi][nj][r] *= alpha;
      }
    }

    // O += P @ V
#pragma unroll
    for (int k0 = 0; k0 < 2; k0++) {
      bf16x8 pf[2];
#pragma unroll
      for (int mi = 0; mi < 2; mi++)
        pf[mi] = *(const bf16x8*)&Ps[wave][(mi * 16 + l15) * 80 + k0 * 32 + quad * 8];
      __builtin_amdgcn_s_setprio(1);
#pragma unroll
      for (int nj = 0; nj < 8; nj++) {
        bf16x8 vf = *(const bf16x8*)&Vt32[(nj * 16 + l15) * 44 + k0 * 16 + quad * 4];
#pragma unroll
        for (int mi = 0; mi < 2; mi++)
          oa[mi][nj] = __builtin_amdgcn_mfma_f32_16x16x32_bf16(pf[mi], vf, oa[mi][nj], 0, 0, 0);
      }
      __builtin_amdgcn_s_setprio(0);
    }
  }

  // epilogue: normalize and store bf16
#pragma unroll
  for (int mi = 0; mi < 2; mi++) {
#pragma unroll
    for (int r = 0; r < 4; r++) {
      int row = wave * 32 + mi * 16 + quad * 4 + r;
      float inv = 1.f / lrow[mi][r];
      u16* op = o + ((size_t)bl * T_SEQ + row) * C_DIM + hh * DHEAD + l15;
#pragma unroll
      for (int nj = 0; nj < 8; nj++)
        op[nj * 16] = f2bf(oa[mi][nj][r] * inv);
    }
  }
}

// ---------------- NormalHead ---------------------------------------------------------
__global__ void head_kernel(const float* __restrict__ x1,
                            const float* __restrict__ bn1g, const float* __restrict__ bn1b,
                            const float* __restrict__ bn1rm, const float* __restrict__ bn1rv,
                            const float* __restrict__ c2W, const float* __restrict__ c2b,
                            const float* __restrict__ bn2g, const float* __restrict__ bn2b,
                            const float* __restrict__ bn2rm, const float* __restrict__ bn2rv,
                            const float* __restrict__ c3W, const float* __restrict__ c3b,
                            float* __restrict__ d1a, float* __restrict__ d2a, float* __restrict__ sca) {
  int r = blockIdx.x * 256 + threadIdx.x;
  if (r >= BN_TOT * T_SEQ) return;
  const float* xp = x1 + (size_t)r * 32;
  float y[32];
  float d1 = 0.f;
#pragma unroll
  for (int oc = 0; oc < 32; oc++) {
    float v = xp[oc];
    float dm = v - bn1rm[oc];
    d1 += dm * dm / bn1rv[oc];
    float t = dm * rsqrtf(bn1rv[oc] + EPS) * bn1g[oc] + bn1b[oc];
    y[oc] = fmaxf(t, 0.f);
  }
  float d2 = 0.f, sacc = 0.f;
#pragma unroll
  for (int o2 = 0; o2 < 16; o2++) {
    float s2 = 0.f;
#pragma unroll
    for (int oc = 0; oc < 32; oc++) s2 = fmaf(y[oc], c2W[o2 * 32 + oc], s2);
    s2 += c2b[o2];
    float dm = s2 - bn2rm[o2];
    d2 += dm * dm / bn2rv[o2];
    float t = dm * rsqrtf(bn2rv[o2] + EPS) * bn2g[o2] + bn2b[o2];
    t = fmaxf(t, 0.f);
    sacc = fmaf(t, c3W[o2], sacc);
  }
  float sc = 1.f / (1.f + expf(-(sacc + c3b[0])));
  d1a[r] = sqrtf(d1);
  d2a[r] = sqrtf(d2);
  sca[r] = sc;
}

__global__ void reduce_kernel(const float* __restrict__ d1a, const float* __restrict__ d2a,
                              const float* __restrict__ sca, float* __restrict__ out) {
  int idx = blockIdx.x * 256 + threadIdx.x;
  if (idx >= 32 * T_SEQ) return;
  int b = idx >> 8, t = idx & 255;
  float s1 = 0.f, s2 = 0.f, ss = 0.f;
  for (int n = 0; n < 10; n++) {
    int r = (b * 10 + n) * T_SEQ + t;
    s1 += d1a[r];
    s2 += d2a[r];
    ss += sca[r];
  }
  out[idx] = (s1 + s2) * ss * 0.01f;
}

extern "C" void kernel_launch(void* const* d_in, const int* in_sizes, int n_in,
                              void* d_out, int out_size, void* d_ws, size_t ws_size,
                              hipStream_t stream) {
  const float* x     = (const float*)d_in[0];
  const float* Wemb  = (const float*)d_in[1];
  const float* bemb  = (const float*)d_in[2];
  const float* ln1g  = (const float*)d_in[3];
  const float* ln1b  = (const float*)d_in[4];
  const float* Wqkv  = (const float*)d_in[5];
  const float* Wo    = (const float*)d_in[6];
  const float* bo    = (const float*)d_in[7];
  const float* ln2g  = (const float*)d_in[8];
  const float* ln2b  = (const float*)d_in[9];
  const float* W1    = (const float*)d_in[10];
  const float* b1    = (const float*)d_in[11];
  const float* W2    = (const float*)d_in[12];
  const float* b2    = (const float*)d_in[13];
  const float* c1W   = (const float*)d_in[14];
  const float* c1b   = (const float*)d_in[15];
  const float* bn1g  = (const float*)d_in[16];
  const float* bn1b  = (const float*)d_in[17];
  const float* bn1rm = (const float*)d_in[18];
  const float* bn1rv = (const float*)d_in[19];
  const float* c2W   = (const float*)d_in[20];
  const float* c2b   = (const float*)d_in[21];
  const float* bn2g  = (const float*)d_in[22];
  const float* bn2b  = (const float*)d_in[23];
  const float* bn2rm = (const float*)d_in[24];
  const float* bn2rv = (const float*)d_in[25];
  const float* c3W   = (const float*)d_in[26];
  const float* c3b   = (const float*)d_in[27];

  char* w = (char*)d_ws;
  size_t off = 0;
  auto alloc = [&](size_t nbytes) {
    void* p = (void*)(w + off);
    off += (nbytes + 255) & ~(size_t)255;
    return p;
  };
  float* h      = (float*)alloc((size_t)BN_TOT * T_SEQ * C_DIM * 4);   // 168 MB
  u16*   u_bf   = (u16*)  alloc((size_t)BN_TOT * T_SEQ * C_DIM * 2);   // 84 MB
  u16*   scratch= (u16*)  alloc((size_t)BN_TOT * T_SEQ * QKV_N * 2);   // 252 MB: xpad / qkv / mlp-mid
  u16*   Wct    = (u16*)  alloc((size_t)3 * C_DIM * D_DIM * 2);
  u16*   Wqkvt  = (u16*)  alloc((size_t)2 * QKV_N * C_DIM * 2);
  u16*   Wot    = (u16*)  alloc((size_t)2 * C_DIM * C_DIM * 2);
  u16*   W1t    = (u16*)  alloc((size_t)2 * C_DIM * C_DIM * 2);
  u16*   W2t    = (u16*)  alloc((size_t)2 * C_DIM * C_DIM * 2);
  float* Wc1t   = (float*)alloc((size_t)C_DIM * 32 * 4);
  float* x1     = (float*)alloc((size_t)BN_TOT * T_SEQ * 32 * 4);
  float* d1a    = (float*)alloc((size_t)BN_TOT * T_SEQ * 4);
  float* d2a    = (float*)alloc((size_t)BN_TOT * T_SEQ * 4);
  float* sca    = (float*)alloc((size_t)BN_TOT * T_SEQ * 4);
  u16* xpad  = scratch;   // 169 MB, dead after conv
  u16* qkvbf = scratch;   // 252 MB, per layer
  u16* midbf = scratch;   // 84 MB mlp mid (qkv dead by then)

  {
    size_t nx4 = (size_t)BN_TOT * 258 * 1024 / 4;
    convert_x<<<(unsigned)((nx4 + 255) / 256), 256, 0, stream>>>(x, xpad);
  }
  prep_wct<<<(3 * C_DIM * D_DIM + 255) / 256, 256, 0, stream>>>(Wemb, Wct);
  for (int l = 0; l < 2; ++l) {
    transpose_w<<<dim3(QKV_N / 32, C_DIM / 32), 256, 0, stream>>>(
        Wqkv + (size_t)l * C_DIM * QKV_N, Wqkvt + (size_t)l * QKV_N * C_DIM, C_DIM, QKV_N);
    transpose_w<<<dim3(C_DIM / 32, C_DIM / 32), 256, 0, stream>>>(
        Wo + (size_t)l * C_DIM * C_DIM, Wot + (size_t)l * C_DIM * C_DIM, C_DIM, C_DIM);
    transpose_w<<<dim3(C_DIM / 32, C_DIM / 32), 256, 0, stream>>>(
        W1 + (size_t)l * C_DIM * C_DIM, W1t + (size_t)l * C_DIM * C_DIM, C_DIM, C_DIM);
    transpose_w<<<dim3(C_DIM / 32, C_DIM / 32), 256, 0, stream>>>(
        W2 + (size_t)l * C_DIM * C_DIM, W2t + (size_t)l * C_DIM * C_DIM, C_DIM, C_DIM);
  }
  prep_c1t<<<(C_DIM * 32 + 255) / 256, 256, 0, stream>>>(c1W, Wc1t);

  // conv as 3 shifted GEMMs over padded bf16 x, relu+bias -> h fp32
  gemm_mfma<3, 3><<<dim3(C_DIM / 128, 2, BN_TOT), 256, 0, stream>>>(
      xpad, 1024, 258, Wct, (size_t)C_DIM * D_DIM, D_DIM, h, nullptr, bemb, C_DIM, 256);

  for (int l = 0; l < 2; ++l) {
    ln_kernel<<<BN_TOT * T_SEQ / 4, 256, 0, stream>>>(h, ln1g + l * C_DIM, ln1b + l * C_DIM, u_bf);
    gemm_mfma<1, 4><<<dim3(QKV_N / 128, 640, 1), 256, 0, stream>>>(
        u_bf, C_DIM, 0, Wqkvt + (size_t)l * QKV_N * C_DIM, 0, C_DIM,
        nullptr, qkvbf, nullptr, QKV_N, 0);
    attn_mfma<<<dim3(NHEAD, BN_TOT), 512, 0, stream>>>(qkvbf, u_bf);
    gemm_mfma<1, 1><<<dim3(C_DIM / 128, 640, 1), 256, 0, stream>>>(
        u_bf, C_DIM, 0, Wot + (size_t)l * C_DIM * C_DIM, 0, C_DIM, h, nullptr, bo + l * C_DIM, C_DIM, 0);
    ln_kernel<<<BN_TOT * T_SEQ / 4, 256, 0, stream>>>(h, ln2g + l * C_DIM, ln2b + l * C_DIM, u_bf);
    gemm_mfma<1, 2><<<dim3(C_DIM / 128, 640, 1), 256, 0, stream>>>(
        u_bf, C_DIM, 0, W1t + (size_t)l * C_DIM * C_DIM, 0, C_DIM, nullptr, midbf, b1 + l * C_DIM, C_DIM, 0);
    gemm_mfma<1, 1><<<dim3(C_DIM / 128, 640, 1), 256, 0, stream>>>(
        midbf, C_DIM, 0, W2t + (size_t)l * C_DIM * C_DIM, 0, C_DIM, h, nullptr, b2 + l * C_DIM, C_DIM, 0);
  }

  gemm_f32<32, 1><<<dim3(1, 81920 / 64), 256, 0, stream>>>(h, Wc1t, x1, c1b, 81920, 32, C_DIM);
  head_kernel<<<(BN_TOT * T_SEQ + 255) / 256, 256, 0, stream>>>(
      x1, bn1g, bn1b, bn1rm, bn1rv, c2W, c2b, bn2g, bn2b, bn2rm, bn2rv, c3W, c3b, d1a, d2a, sca);
  reduce_kernel<<<32, 256, 0, stream>>>(d1a, d2a, sca, (float*)d_out);
}

// Round 2
// 2563.719 us; speedup vs baseline: 1.1260x; 1.1260x over previous
//
#include <hip/hip_runtime.h>
#include <math.h>

#define T_SEQ 256
#define C_DIM 512
#define D_DIM 1024
#define BN_TOT 320
#define NHEAD 4
#define DHEAD 128
#define QKV_N 1536
#define EPS 1e-5f
#define ATT_SCALE 0.08838834764831845f

typedef unsigned short u16;
typedef unsigned int u32;
typedef __attribute__((ext_vector_type(8))) short bf16x8;
typedef __attribute__((ext_vector_type(4))) float f32x4;

__device__ __forceinline__ u16 f2bf(float f) {
  union { float f; u32 u; } v; v.f = f;
  u32 r = v.u + 0x7fffu + ((v.u >> 16) & 1u);
  return (u16)(r >> 16);
}

__device__ __forceinline__ void gload_lds16(const u16* g, u16* l) {
  __builtin_amdgcn_global_load_lds((const __attribute__((address_space(1))) u32*)g,
                                   (__attribute__((address_space(3))) u32*)l, 16, 0, 0);
}

// ---------------- prep kernels -------------------------------------------------------
// 4 elems/thread: float4 in, ushort4 out (G13 vectorization)
__global__ void convert_x(const float* __restrict__ x, u16* __restrict__ xpad) {
  size_t i4 = ((size_t)blockIdx.x * 256 + threadIdx.x) * 4;
  if (i4 >= (size_t)BN_TOT * 258 * 1024) return;
  size_t row = i4 >> 10; int col = (int)(i4 & 1023);
  int bn = (int)(row / 258), tr = (int)(row % 258);
  ushort4 o;
  if (tr == 0 || tr == 257) {
    o.x = 0; o.y = 0; o.z = 0; o.w = 0;
  } else {
    float4 v = *(const float4*)&x[((size_t)bn * 256 + tr - 1) * 1024 + col];
    o.x = f2bf(v.x); o.y = f2bf(v.y); o.z = f2bf(v.z); o.w = f2bf(v.w);
  }
  *(ushort4*)&xpad[i4] = o;
}

__global__ void prep_wct(const float* __restrict__ Wemb, u16* __restrict__ Wct) {
  int idx = blockIdx.x * 256 + threadIdx.x;
  if (idx >= 3 * C_DIM * D_DIM) return;
  int d = idx & 1023;
  int c = (idx >> 10) & 511;
  int s = idx >> 19;
  Wct[idx] = f2bf(Wemb[(c * D_DIM + d) * 3 + s]);
}

// tiled transpose: src [K][N] fp32 -> dst [N][K] bf16. 32x32 tiles, coalesced both sides.
__launch_bounds__(256)
__global__ void transpose_w(const float* __restrict__ src, u16* __restrict__ dst, int K, int N) {
  __shared__ float t[32][33];
  int tid = threadIdx.x;
  int n0 = blockIdx.x * 32, k0 = blockIdx.y * 32;
  int r = tid >> 3, c4 = (tid & 7) * 4;
  float4 v = *(const float4*)&src[(size_t)(k0 + r) * N + n0 + c4];
  t[r][c4 + 0] = v.x; t[r][c4 + 1] = v.y; t[r][c4 + 2] = v.z; t[r][c4 + 3] = v.w;
  __syncthreads();
  ushort4 o;
  o.x = f2bf(t[c4 + 0][r]);
  o.y = f2bf(t[c4 + 1][r]);
  o.z = f2bf(t[c4 + 2][r]);
  o.w = f2bf(t[c4 + 3][r]);
  *(ushort4*)&dst[(size_t)(n0 + r) * K + k0 + c4] = o;
}

__global__ void prep_c1t(const float* __restrict__ c1W, float* __restrict__ Wt) {
  int idx = blockIdx.x * 256 + threadIdx.x;
  if (idx >= C_DIM * 32) return;
  int n = idx & 31;
  int k = idx >> 5;
  Wt[idx] = c1W[n * C_DIM + k];
}

// ---------------- bf16 MFMA GEMM -----------------------------------------------------
// EPI: 0 = store fp32, 1 = C += acc+bias (fp32), 2 = Cbf = bf16(gelu(acc+bias)),
//      3 = C = relu(acc+bias) fp32, 4 = Cbf = bf16(acc)
// T2 LDS swizzle (rule #21 compliant): global_load_lds dest stays LINEAR; the
// global SOURCE column is pre-swizzled per-lane (col ^= srow*8, an involution
// since row&7 == srow), and the ds_read address XORs the same pattern
// ((l15&7)*8). Each quarter-wave's 16-B chunks then spread over 8 bank slots
// (2 lanes/slot = free) instead of piling 16 lanes on one slot (16-way).
template <int S, int EPI>
__launch_bounds__(256)
__global__ void gemm_mfma(const u16* __restrict__ A, int lda, int aRowsPerZ,
                          const u16* __restrict__ Bt, size_t bShift, int K,
                          float* __restrict__ C, u16* __restrict__ Cbf,
                          const float* __restrict__ bias, int N, int cRowsPerZ) {
  __shared__ u16 lds[16384];
  u16* Alds = lds;
  u16* Blds = lds + 8192;

  const int tid = threadIdx.x;
  const int lane = tid & 63;
  const int wave = tid >> 6;
  const int wm = wave >> 1, wn = wave & 1;
  const int quad = lane >> 4;
  const int l15 = lane & 15;
  const int srow = lane >> 3;                    // 0..7 within staging group
  const int scol = ((lane & 7) ^ srow) * 8;      // swizzled source col (u16)
  const int xk = (l15 & 7) * 8;                  // read-side XOR (u16)

  // T1: XCD-aware bijective chunked swizzle (nwg % 8 == 0 for all our launches).
  unsigned gx = gridDim.x, gy = gridDim.y, gz = gridDim.z;
  unsigned orig = (blockIdx.z * gy + blockIdx.y) * gx + blockIdx.x;
  unsigned nwg = gx * gy * gz;
  unsigned wg = orig;
  if ((nwg & 7u) == 0u) wg = (orig & 7u) * (nwg >> 3) + (orig >> 3);
  unsigned bx = wg % gx;
  unsigned tmp = wg / gx;
  unsigned by = tmp % gy;
  unsigned bz = tmp / gy;

  const int n0 = bx * 128;
  const int arow0 = bz * aRowsPerZ + by * 128;
  const int crow0 = bz * cRowsPerZ + by * 128;

  f32x4 acc[4][4] = {};

  for (int s = 0; s < S; ++s) {
    const u16* Ab = A + ((size_t)arow0 + s) * (size_t)lda;
    const u16* Bb = Bt + (size_t)s * bShift;
    for (int k0 = 0; k0 < K; k0 += 64) {
#pragma unroll
      for (int c = 0; c < 4; ++c) {
        int chunk = wave * 4 + c;
        gload_lds16(Ab + (size_t)(chunk * 8 + srow) * lda + k0 + scol,
                    Alds + chunk * 512);
      }
#pragma unroll
      for (int c = 0; c < 4; ++c) {
        int chunk = wave * 4 + c;
        gload_lds16(Bb + (size_t)(n0 + chunk * 8 + srow) * K + k0 + scol,
                    Blds + chunk * 512);
      }
      __syncthreads();
#pragma unroll
      for (int kk = 0; kk < 64; kk += 32) {
        bf16x8 af[4], bfr[4];
#pragma unroll
        for (int mt = 0; mt < 4; ++mt)
          af[mt] = *(const bf16x8*)&Alds[(wm * 64 + mt * 16 + l15) * 64 + ((kk + quad * 8) ^ xk)];
#pragma unroll
        for (int nt = 0; nt < 4; ++nt)
          bfr[nt] = *(const bf16x8*)&Blds[(wn * 64 + nt * 16 + l15) * 64 + ((kk + quad * 8) ^ xk)];
#pragma unroll
        for (int mt = 0; mt < 4; ++mt)
#pragma unroll
          for (int nt = 0; nt < 4; ++nt)
            acc[mt][nt] = __builtin_amdgcn_mfma_f32_16x16x32_bf16(af[mt], bfr[nt], acc[mt][nt], 0, 0, 0);
      }
      __syncthreads();
    }
  }

#pragma unroll
  for (int mt = 0; mt < 4; ++mt) {
#pragma unroll
    for (int nt = 0; nt < 4; ++nt) {
      int col = n0 + wn * 64 + nt * 16 + l15;
      float bv = 0.f;
      if constexpr (EPI == 1 || EPI == 2 || EPI == 3) bv = bias[col];
#pragma unroll
      for (int r = 0; r < 4; ++r) {
        size_t row = (size_t)crow0 + wm * 64 + mt * 16 + quad * 4 + r;
        float v = acc[mt][nt][r];
        if constexpr (EPI == 0) {
          C[row * N + col] = v;
        } else if constexpr (EPI == 1) {
          C[row * N + col] += v + bv;
        } else if constexpr (EPI == 2) {
          float t = v + bv;
          Cbf[row * N + col] = f2bf(t * 0.5f * (1.f + erff(t * 0.70710678118f)));
        } else if constexpr (EPI == 3) {
          C[row * N + col] = fmaxf(v + bv, 0.f);
        } else {
          Cbf[row * N + col] = f2bf(v);
        }
      }
    }
  }
}

// ---------------- small fp32 GEMM (head c1: N=32) ------------------------------------
template <int NT, int EPI>
__launch_bounds__(256)
__global__ void gemm_f32(const float* __restrict__ A, const float* __restrict__ B,
                         float* __restrict__ C, const float* __restrict__ bias,
                         int M, int N, int K) {
  __shared__ __align__(16) float As[16][68];
  __shared__ __align__(16) float Bs[16][NT + 4];
  int tid = threadIdx.x;
  int tx = tid & 15, ty = tid >> 4;
  int n0 = blockIdx.x * NT, m0 = blockIdx.y * 64;
  constexpr int TN = NT / 16;
  float acc[4][TN] = {};
  int arow = tid >> 2, akg = (tid & 3) * 4;
  int bk, bng;
  if (NT == 64) { bk = tid >> 4; bng = (tid & 15) * 4; }
  else          { bk = tid >> 3; bng = (tid & 7) * 4; }
  bool bload = (NT == 64) || (tid < 128);
  const float* Ap = A + (size_t)(m0 + arow) * K + akg;
  const float* Bp = B + (size_t)bk * N + n0 + bng;
  for (int k0 = 0; k0 < K; k0 += 16) {
    float4 av = *(const float4*)(Ap + k0);
    float4 bv = make_float4(0.f, 0.f, 0.f, 0.f);
    if (bload) bv = *(const float4*)(Bp + (size_t)k0 * N);
    __syncthreads();
    As[akg + 0][arow] = av.x; As[akg + 1][arow] = av.y;
    As[akg + 2][arow] = av.z; As[akg + 3][arow] = av.w;
    if (bload) *(float4*)&Bs[bk][bng] = bv;
    __syncthreads();
#pragma unroll
    for (int k = 0; k < 16; ++k) {
      float4 a4 = *(const float4*)&As[k][ty * 4];
      float a[4] = {a4.x, a4.y, a4.z, a4.w};
      float b[TN];
#pragma unroll
      for (int j = 0; j < TN; j++) b[j] = Bs[k][tx * TN + j];
#pragma unroll
      for (int i = 0; i < 4; i++)
#pragma unroll
        for (int j = 0; j < TN; j++) acc[i][j] = fmaf(a[i], b[j], acc[i][j]);
    }
  }
#pragma unroll
  for (int i = 0; i < 4; i++) {
    size_t row = m0 + ty * 4 + i;
    float* Cp = C + row * (size_t)N + n0 + tx * TN;
#pragma unroll
    for (int j = 0; j < TN; j++) {
      float v = acc[i][j];
      if (EPI >= 1) v += bias[n0 + tx * TN + j];
      Cp[j] = v;
    }
  }
}

// ---------------- LayerNorm over last dim (512), bf16 out ----------------------------
// wave-per-row: float4 loads, pure shfl_xor reduce, ushort4 stores. 4 rows / block.
__launch_bounds__(256)
__global__ void ln_kernel(const float* __restrict__ h, const float* __restrict__ g,
                          const float* __restrict__ b, u16* __restrict__ u) {
  int row = blockIdx.x * 4 + (threadIdx.x >> 6);
  int lane = threadIdx.x & 63;
  const float* hp = h + (size_t)row * C_DIM + lane * 8;
  float4 a0 = *(const float4*)hp;
  float4 a1 = *(const float4*)(hp + 4);
  float s = a0.x + a0.y + a0.z + a0.w + a1.x + a1.y + a1.z + a1.w;
#pragma unroll
  for (int o = 32; o > 0; o >>= 1) s += __shfl_xor(s, o);
  float mu = s * (1.f / 512.f);
  float d[8] = {a0.x - mu, a0.y - mu, a0.z - mu, a0.w - mu,
                a1.x - mu, a1.y - mu, a1.z - mu, a1.w - mu};
  float q = 0.f;
#pragma unroll
  for (int j = 0; j < 8; ++j) q += d[j] * d[j];
#pragma unroll
  for (int o = 32; o > 0; o >>= 1) q += __shfl_xor(q, o);
  float rs = rsqrtf(q * (1.f / 512.f) + EPS);
  const float* gp = g + lane * 8;
  const float* bp = b + lane * 8;
  float4 g0 = *(const float4*)gp, g1 = *(const float4*)(gp + 4);
  float4 b0 = *(const float4*)bp, b1 = *(const float4*)(bp + 4);
  float gv[8] = {g0.x, g0.y, g0.z, g0.w, g1.x, g1.y, g1.z, g1.w};
  float bv[8] = {b0.x, b0.y, b0.z, b0.w, b1.x, b1.y, b1.z, b1.w};
  ushort4 o0, o1;
  o0.x = f2bf(d[0] * rs * gv[0] + bv[0]);
  o0.y = f2bf(d[1] * rs * gv[1] + bv[1]);
  o0.z = f2bf(d[2] * rs * gv[2] + bv[2]);
  o0.w = f2bf(d[3] * rs * gv[3] + bv[3]);
  o1.x = f2bf(d[4] * rs * gv[4] + bv[4]);
  o1.y = f2bf(d[5] * rs * gv[5] + bv[5]);
  o1.z = f2bf(d[6] * rs * gv[6] + bv[6]);
  o1.w = f2bf(d[7] * rs * gv[7] + bv[7]);
  u16* up = u + (size_t)row * C_DIM + lane * 8;
  *(ushort4*)up = o0;
  *(ushort4*)(up + 4) = o1;
}

// ---------------- MFMA flash attention: block = (head, bn), 8 waves ------------------
// qkv bf16 [bn][t][1536]; out bf16 [bn][t][512] at col hh*128.
__launch_bounds__(512, 2)
__global__ void attn_mfma(const u16* __restrict__ qkv, u16* __restrict__ o) {
  __shared__ u16 Ks[64 * 136];        // [kk][d], pad 136
  __shared__ u32 Vt32[128 * 44];      // [d][kk-pair], pad 44 dwords (=88 u16)
  __shared__ u16 Ps[8][32 * 80];      // per-wave P [m][kk], pad 80

  const int tid = threadIdx.x;
  const int lane = tid & 63, wave = tid >> 6;
  const int quad = lane >> 4, l15 = lane & 15;
  const int hh = blockIdx.x, bl = blockIdx.y;
  const u16* base = qkv + (size_t)bl * T_SEQ * QKV_N;

  // Q fragments in registers: rows wave*32 + mi*16 + l15
  bf16x8 qf[2][4];
#pragma unroll
  for (int mi = 0; mi < 2; mi++) {
    int row = wave * 32 + mi * 16 + l15;
    const u16* qp = base + (size_t)row * QKV_N + hh * DHEAD + quad * 8;
#pragma unroll
    for (int k0 = 0; k0 < 4; k0++)
      qf[mi][k0] = *(const bf16x8*)(qp + k0 * 32);
  }

  f32x4 oa[2][8] = {};
  float mrow[2][4], lrow[2][4];
#pragma unroll
  for (int mi = 0; mi < 2; mi++)
#pragma unroll
    for (int r = 0; r < 4; r++) { mrow[mi][r] = -1e30f; lrow[mi][r] = 0.f; }

  for (int kt = 0; kt < 4; kt++) {
    __syncthreads();
    // K tile 64x128 -> Ks (16 elems / thread)
    {
      int kk = tid >> 3, dbase = (tid & 7) * 16;
      const u16* kp = base + (size_t)(kt * 64 + kk) * QKV_N + C_DIM + hh * DHEAD + dbase;
      uint4 a = *(const uint4*)kp;
      uint4 b = *(const uint4*)(kp + 8);
      *(uint4*)&Ks[kk * 136 + dbase] = a;
      *(uint4*)&Ks[kk * 136 + dbase + 8] = b;
    }
    // V tile 64x128 -> Vt32 transposed (pairs of kk packed in u32)
    {
      int kkp = tid >> 4, dbase = (tid & 15) * 8;
      const u16* vp = base + (size_t)(kt * 64 + kkp * 2) * QKV_N + 2 * C_DIM + hh * DHEAD + dbase;
      union { uint4 u; u16 h[8]; } va, vb;
      va.u = *(const uint4*)vp;
      vb.u = *(const uint4*)(vp + QKV_N);
#pragma unroll
      for (int j = 0; j < 8; j++)
        Vt32[(dbase + j) * 44 + kkp] = (u32)va.h[j] | ((u32)vb.h[j] << 16);
    }
    __syncthreads();

    // S = Q @ K^T (raw, scaled later)
    f32x4 sa[2][4] = {};
#pragma unroll
    for (int k0 = 0; k0 < 4; k0++) {
      bf16x8 kf[4];
#pragma unroll
      for (int ni = 0; ni < 4; ni++)
        kf[ni] = *(const bf16x8*)&Ks[(ni * 16 + l15) * 136 + k0 * 32 + quad * 8];
      __builtin_amdgcn_s_setprio(1);
#pragma unroll
      for (int mi = 0; mi < 2; mi++)
#pragma unroll
        for (int ni = 0; ni < 4; ni++)
          sa[mi][ni] = __builtin_amdgcn_mfma_f32_16x16x32_bf16(qf[mi][k0], kf[ni], sa[mi][ni], 0, 0, 0);
      __builtin_amdgcn_s_setprio(0);
    }

    // online softmax (rows = quad*4+r within 16-tile; 16 lanes l15 share a row)
#pragma unroll
    for (int mi = 0; mi < 2; mi++) {
#pragma unroll
      for (int r = 0; r < 4; r++) {
        float mx = fmaxf(fmaxf(sa[mi][0][r], sa[mi][1][r]), fmaxf(sa[mi][2][r], sa[mi][3][r]));
        mx = fmaxf(mx, __shfl_xor(mx, 1));
        mx = fmaxf(mx, __shfl_xor(mx, 2));
        mx = fmaxf(mx, __shfl_xor(mx, 4));
        mx = fmaxf(mx, __shfl_xor(mx, 8));
        mx *= ATT_SCALE;
        float mnew = fmaxf(mrow[mi][r], mx);
        float alpha = __expf(mrow[mi][r] - mnew);
        mrow[mi][r] = mnew;
        float rs = 0.f;
#pragma unroll
        for (int ni = 0; ni < 4; ni++) {
          float p = __expf(sa[mi][ni][r] * ATT_SCALE - mnew);
          rs += p;
          Ps[wave][(mi * 16 + quad * 4 + r) * 80 + ni * 16 + l15] = f2bf(p);
        }
        rs += __shfl_xor(rs, 1);
        rs += __shfl_xor(rs, 2);
        rs += __shfl_xor(rs, 4);
        rs += __shfl_xor(rs, 8);
        lrow[mi][r] = lrow[mi][r] * alpha + rs;
#pragma unroll
        for (int nj = 0; nj < 8; nj++) oa[mi][nj][r] *= alpha;
      }
    }

    // O += P @ V
#pragma unroll
    for (int k0 = 0; k0 < 2; k0++) {
      bf16x8 pf[2];
#pragma unroll
      for (int mi = 0; mi < 2; mi++)
        pf[mi] = *(const bf16x8*)&Ps[wave][(mi * 16 + l15) * 80 + k0 * 32 + quad * 8];
      __builtin_amdgcn_s_setprio(1);
#pragma unroll
      for (int nj = 0; nj < 8; nj++) {
        bf16x8 vf = *(const bf16x8*)&Vt32[(nj * 16 + l15) * 44 + k0 * 16 + quad * 4];
#pragma unroll
        for (int mi = 0; mi < 2; mi++)
          oa[mi][nj] = __builtin_amdgcn_mfma_f32_16x16x32_bf16(pf[mi], vf, oa[mi][nj], 0, 0, 0);
      }
      __builtin_amdgcn_s_setprio(0);
    }
  }

  // epilogue: normalize and store bf16
#pragma unroll
  for (int mi = 0; mi < 2; mi++) {
#pragma unroll
    for (int r = 0; r < 4; r++) {
      int row = wave * 32 + mi * 16 + quad * 4 + r;
      float inv = 1.f / lrow[mi][r];
      u16* op = o + ((size_t)bl * T_SEQ + row) * C_DIM + hh * DHEAD + l15;
#pragma unroll
      for (int nj = 0; nj < 8; nj++)
        op[nj * 16] = f2bf(oa[mi][nj][r] * inv);
    }
  }
}

// ---------------- NormalHead ---------------------------------------------------------
__global__ void head_kernel(const float* __restrict__ x1,
                            const float* __restrict__ bn1g, const float* __restrict__ bn1b,
                            const float* __restrict__ bn1rm, const float* __restrict__ bn1rv,
                            const float* __restrict__ c2W, const float* __restrict__ c2b,
                            const float* __restrict__ bn2g, const float* __restrict__ bn2b,
                            const float* __restrict__ bn2rm, const float* __restrict__ bn2rv,
                            const float* __restrict__ c3W, const float* __restrict__ c3b,
                            float* __restrict__ d1a, float* __restrict__ d2a, float* __restrict__ sca) {
  int r = blockIdx.x * 256 + threadIdx.x;
  if (r >= BN_TOT * T_SEQ) return;
  const float* xp = x1 + (size_t)r * 32;
  float y[32];
  float d1 = 0.f;
#pragma unroll
  for (int oc = 0; oc < 32; oc++) {
    float v = xp[oc];
    float dm = v - bn1rm[oc];
    d1 += dm * dm / bn1rv[oc];
    float t = dm * rsqrtf(bn1rv[oc] + EPS) * bn1g[oc] + bn1b[oc];
    y[oc] = fmaxf(t, 0.f);
  }
  float d2 = 0.f, sacc = 0.f;
#pragma unroll
  for (int o2 = 0; o2 < 16; o2++) {
    float s2 = 0.f;
#pragma unroll
    for (int oc = 0; oc < 32; oc++) s2 = fmaf(y[oc], c2W[o2 * 32 + oc], s2);
    s2 += c2b[o2];
    float dm = s2 - bn2rm[o2];
    d2 += dm * dm / bn2rv[o2];
    float t = dm * rsqrtf(bn2rv[o2] + EPS) * bn2g[o2] + bn2b[o2];
    t = fmaxf(t, 0.f);
    sacc = fmaf(t, c3W[o2], sacc);
  }
  float sc = 1.f / (1.f + expf(-(sacc + c3b[0])));
  d1a[r] = sqrtf(d1);
  d2a[r] = sqrtf(d2);
  sca[r] = sc;
}

__global__ void reduce_kernel(const float* __restrict__ d1a, const float* __restrict__ d2a,
                              const float* __restrict__ sca, float* __restrict__ out) {
  int idx = blockIdx.x * 256 + threadIdx.x;
  if (idx >= 32 * T_SEQ) return;
  int b = idx >> 8, t = idx & 255;
  float s1 = 0.f, s2 = 0.f, ss = 0.f;
  for (int n = 0; n < 10; n++) {
    int r = (b * 10 + n) * T_SEQ + t;
    s1 += d1a[r];
    s2 += d2a[r];
    ss += sca[r];
  }
  out[idx] = (s1 + s2) * ss * 0.01f;
}

extern "C" void kernel_launch(void* const* d_in, const int* in_sizes, int n_in,
                              void* d_out, int out_size, void* d_ws, size_t ws_size,
                              hipStream_t stream) {
  const float* x     = (const float*)d_in[0];
  const float* Wemb  = (const float*)d_in[1];
  const float* bemb  = (const float*)d_in[2];
  const float* ln1g  = (const float*)d_in[3];
  const float* ln1b  = (const float*)d_in[4];
  const float* Wqkv  = (const float*)d_in[5];
  const float* Wo    = (const float*)d_in[6];
  const float* bo    = (const float*)d_in[7];
  const float* ln2g  = (const float*)d_in[8];
  const float* ln2b  = (const float*)d_in[9];
  const float* W1    = (const float*)d_in[10];
  const float* b1    = (const float*)d_in[11];
  const float* W2    = (const float*)d_in[12];
  const float* b2    = (const float*)d_in[13];
  const float* c1W   = (const float*)d_in[14];
  const float* c1b   = (const float*)d_in[15];
  const float* bn1g  = (const float*)d_in[16];
  const float* bn1b  = (const float*)d_in[17];
  const float* bn1rm = (const float*)d_in[18];
  const float* bn1rv = (const float*)d_in[19];
  const float* c2W   = (const float*)d_in[20];
  const float* c2b   = (const float*)d_in[21];
  const float* bn2g  = (const float*)d_in[22];
  const float* bn2b  = (const float*)d_in[23];
  const float* bn2rm = (const float*)d_in[24];
  const float* bn2rv = (const float*)d_in[25];
  const float* c3W   = (const float*)d_in[26];
  const float* c3b   = (const float*)d_in[27];

  char* w = (char*)d_ws;
  size_t off = 0;
  auto alloc = [&](size_t nbytes) {
    void* p = (void*)(w + off);
    off += (nbytes + 255) & ~(size_t)255;
    return p;
  };
  float* h      = (float*)alloc((size_t)BN_TOT * T_SEQ * C_DIM * 4);   // 168 MB
  u16*   u_bf   = (u16*)  alloc((size_t)BN_TOT * T_SEQ * C_DIM * 2);   // 84 MB
  u16*   scratch= (u16*)  alloc((size_t)BN_TOT * T_SEQ * QKV_N * 2);   // 252 MB: xpad / qkv / mlp-mid
  u16*   Wct    = (u16*)  alloc((size_t)3 * C_DIM * D_DIM * 2);
  u16*   Wqkvt  = (u16*)  alloc((size_t)2 * QKV_N * C_DIM * 2);
  u16*   Wot    = (u16*)  alloc((size_t)2 * C_DIM * C_DIM * 2);
  u16*   W1t    = (u16*)  alloc((size_t)2 * C_DIM * C_DIM * 2);
  u16*   W2t    = (u16*)  alloc((size_t)2 * C_DIM * C_DIM * 2);
  float* Wc1t   = (float*)alloc((size_t)C_DIM * 32 * 4);
  float* x1     = (float*)alloc((size_t)BN_TOT * T_SEQ * 32 * 4);
  float* d1a    = (float*)alloc((size_t)BN_TOT * T_SEQ * 4);
  float* d2a    = (float*)alloc((size_t)BN_TOT * T_SEQ * 4);
  float* sca    = (float*)alloc((size_t)BN_TOT * T_SEQ * 4);
  u16* xpad  = scratch;   // 169 MB, dead after conv
  u16* qkvbf = scratch;   // 252 MB, per layer
  u16* midbf = scratch;   // 84 MB mlp mid (qkv dead by then)

  {
    size_t nx4 = (size_t)BN_TOT * 258 * 1024 / 4;
    convert_x<<<(unsigned)((nx4 + 255) / 256), 256, 0, stream>>>(x, xpad);
  }
  prep_wct<<<(3 * C_DIM * D_DIM + 255) / 256, 256, 0, stream>>>(Wemb, Wct);
  for (int l = 0; l < 2; ++l) {
    transpose_w<<<dim3(QKV_N / 32, C_DIM / 32), 256, 0, stream>>>(
        Wqkv + (size_t)l * C_DIM * QKV_N, Wqkvt + (size_t)l * QKV_N * C_DIM, C_DIM, QKV_N);
    transpose_w<<<dim3(C_DIM / 32, C_DIM / 32), 256, 0, stream>>>(
        Wo + (size_t)l * C_DIM * C_DIM, Wot + (size_t)l * C_DIM * C_DIM, C_DIM, C_DIM);
    transpose_w<<<dim3(C_DIM / 32, C_DIM / 32), 256, 0, stream>>>(
        W1 + (size_t)l * C_DIM * C_DIM, W1t + (size_t)l * C_DIM * C_DIM, C_DIM, C_DIM);
    transpose_w<<<dim3(C_DIM / 32, C_DIM / 32), 256, 0, stream>>>(
        W2 + (size_t)l * C_DIM * C_DIM, W2t + (size_t)l * C_DIM * C_DIM, C_DIM, C_DIM);
  }
  prep_c1t<<<(C_DIM * 32 + 255) / 256, 256, 0, stream>>>(c1W, Wc1t);

  // conv as 3 shifted GEMMs over padded bf16 x, relu+bias -> h fp32
  gemm_mfma<3, 3><<<dim3(C_DIM / 128, 2, BN_TOT), 256, 0, stream>>>(
      xpad, 1024, 258, Wct, (size_t)C_DIM * D_DIM, D_DIM, h, nullptr, bemb, C_DIM, 256);

  for (int l = 0; l < 2; ++l) {
    ln_kernel<<<BN_TOT * T_SEQ / 4, 256, 0, stream>>>(h, ln1g + l * C_DIM, ln1b + l * C_DIM, u_bf);
    gemm_mfma<1, 4><<<dim3(QKV_N / 128, 640, 1), 256, 0, stream>>>(
        u_bf, C_DIM, 0, Wqkvt + (size_t)l * QKV_N * C_DIM, 0, C_DIM,
        nullptr, qkvbf, nullptr, QKV_N, 0);
    attn_mfma<<<dim3(NHEAD, BN_TOT), 512, 0, stream>>>(qkvbf, u_bf);
    gemm_mfma<1, 1><<<dim3(C_DIM / 128, 640, 1), 256, 0, stream>>>(
        u_bf, C_DIM, 0, Wot + (size_t)l * C_DIM * C_DIM, 0, C_DIM, h, nullptr, bo + l * C_DIM, C_DIM, 0);
    ln_kernel<<<BN_TOT * T_SEQ / 4, 256, 0, stream>>>(h, ln2g + l * C_DIM, ln2b + l * C_DIM, u_bf);
    gemm_mfma<1, 2><<<dim3(C_DIM / 128, 640, 1), 256, 0, stream>>>(
        u_bf, C_DIM, 0, W1t + (size_t)l * C_DIM * C_DIM, 0, C_DIM, nullptr, midbf, b1 + l * C_DIM, C_DIM, 0);
    gemm_mfma<1, 1><<<dim3(C_DIM / 128, 640, 1), 256, 0, stream>>>(
        midbf, C_DIM, 0, W2t + (size_t)l * C_DIM * C_DIM, 0, C_DIM, h, nullptr, b2 + l * C_DIM, C_DIM, 0);
  }

  gemm_f32<32, 1><<<dim3(1, 81920 / 64), 256, 0, stream>>>(h, Wc1t, x1, c1b, 81920, 32, C_DIM);
  head_kernel<<<(BN_TOT * T_SEQ + 255) / 256, 256, 0, stream>>>(
      x1, bn1g, bn1b, bn1rm, bn1rv, c2W, c2b, bn2g, bn2b, bn2rm, bn2rv, c3W, c3b, d1a, d2a, sca);
  reduce_kernel<<<32, 256, 0, stream>>>(d1a, d2a, sca, (float*)d_out);
}

// Round 3
// 2460.344 us; speedup vs baseline: 1.1733x; 1.0420x over previous
//
#include <hip/hip_runtime.h>
#include <math.h>

#define T_SEQ 256
#define C_DIM 512
#define D_DIM 1024
#define BN_TOT 320
#define NHEAD 4
#define DHEAD 128
#define QKV_N 1536
#define EPS 1e-5f
#define ATT_SCALE 0.08838834764831845f

typedef unsigned short u16;
typedef unsigned int u32;
typedef __attribute__((ext_vector_type(8))) short bf16x8;
typedef __attribute__((ext_vector_type(4))) float f32x4;

__device__ __forceinline__ u16 f2bf(float f) {
  union { float f; u32 u; } v; v.f = f;
  u32 r = v.u + 0x7fffu + ((v.u >> 16) & 1u);
  return (u16)(r >> 16);
}

__device__ __forceinline__ void gload_lds16(const u16* g, u16* l) {
  __builtin_amdgcn_global_load_lds((const __attribute__((address_space(1))) u32*)g,
                                   (__attribute__((address_space(3))) u32*)l, 16, 0, 0);
}

// ---------------- prep kernels -------------------------------------------------------
__global__ void convert_x(const float* __restrict__ x, u16* __restrict__ xpad) {
  size_t i4 = ((size_t)blockIdx.x * 256 + threadIdx.x) * 4;
  if (i4 >= (size_t)BN_TOT * 258 * 1024) return;
  size_t row = i4 >> 10; int col = (int)(i4 & 1023);
  int bn = (int)(row / 258), tr = (int)(row % 258);
  ushort4 o;
  if (tr == 0 || tr == 257) {
    o.x = 0; o.y = 0; o.z = 0; o.w = 0;
  } else {
    float4 v = *(const float4*)&x[((size_t)bn * 256 + tr - 1) * 1024 + col];
    o.x = f2bf(v.x); o.y = f2bf(v.y); o.z = f2bf(v.z); o.w = f2bf(v.w);
  }
  *(ushort4*)&xpad[i4] = o;
}

__global__ void prep_wct(const float* __restrict__ Wemb, u16* __restrict__ Wct) {
  int idx = blockIdx.x * 256 + threadIdx.x;
  if (idx >= 3 * C_DIM * D_DIM) return;
  int d = idx & 1023;
  int c = (idx >> 10) & 511;
  int s = idx >> 19;
  Wct[idx] = f2bf(Wemb[(c * D_DIM + d) * 3 + s]);
}

// tiled transpose: src [K][N] fp32 -> dst [N][K] bf16. 32x32 tiles, coalesced both sides.
__launch_bounds__(256)
__global__ void transpose_w(const float* __restrict__ src, u16* __restrict__ dst, int K, int N) {
  __shared__ float t[32][33];
  int tid = threadIdx.x;
  int n0 = blockIdx.x * 32, k0 = blockIdx.y * 32;
  int r = tid >> 3, c4 = (tid & 7) * 4;
  float4 v = *(const float4*)&src[(size_t)(k0 + r) * N + n0 + c4];
  t[r][c4 + 0] = v.x; t[r][c4 + 1] = v.y; t[r][c4 + 2] = v.z; t[r][c4 + 3] = v.w;
  __syncthreads();
  ushort4 o;
  o.x = f2bf(t[c4 + 0][r]);
  o.y = f2bf(t[c4 + 1][r]);
  o.z = f2bf(t[c4 + 2][r]);
  o.w = f2bf(t[c4 + 3][r]);
  *(ushort4*)&dst[(size_t)(n0 + r) * K + k0 + c4] = o;
}

__global__ void prep_c1t(const float* __restrict__ c1W, float* __restrict__ Wt) {
  int idx = blockIdx.x * 256 + threadIdx.x;
  if (idx >= C_DIM * 32) return;
  int n = idx & 31;
  int k = idx >> 5;
  Wt[idx] = c1W[n * C_DIM + k];
}

// ---------------- bf16 MFMA GEMM -----------------------------------------------------
// EPI: 0 = store fp32, 1 = C += acc+bias (fp32), 2 = Cbf = bf16(gelu(acc+bias)),
//      3 = C = relu(acc+bias) fp32, 4 = Cbf = bf16(acc)
// T2 LDS swizzle (rule #21): linear gload_lds dest, pre-swizzled global source col,
// matching XOR on ds_read. Epilogue: LDS-transposed so each thread owns 4
// consecutive cols -> float4/ushort4 global IO (512-B segments per 32 lanes).
template <int S, int EPI>
__launch_bounds__(256)
__global__ void gemm_mfma(const u16* __restrict__ A, int lda, int aRowsPerZ,
                          const u16* __restrict__ Bt, size_t bShift, int K,
                          float* __restrict__ C, u16* __restrict__ Cbf,
                          const float* __restrict__ bias, int N, int cRowsPerZ) {
  __shared__ __align__(16) float smem_f[64 * 132];   // 33792 B; aliased as u16 for K-loop
  u16* lds = (u16*)smem_f;
  u16* Alds = lds;
  u16* Blds = lds + 8192;
  float (*ldsT)[132] = (float (*)[132])smem_f;

  const int tid = threadIdx.x;
  const int lane = tid & 63;
  const int wave = tid >> 6;
  const int wm = wave >> 1, wn = wave & 1;
  const int quad = lane >> 4;
  const int l15 = lane & 15;
  const int srow = lane >> 3;                    // 0..7 within staging group
  const int scol = ((lane & 7) ^ srow) * 8;      // swizzled source col (u16)
  const int xk = (l15 & 7) * 8;                  // read-side XOR (u16)

  // T1: XCD-aware bijective chunked swizzle (nwg % 8 == 0 for all our launches).
  unsigned gx = gridDim.x, gy = gridDim.y, gz = gridDim.z;
  unsigned orig = (blockIdx.z * gy + blockIdx.y) * gx + blockIdx.x;
  unsigned nwg = gx * gy * gz;
  unsigned wg = orig;
  if ((nwg & 7u) == 0u) wg = (orig & 7u) * (nwg >> 3) + (orig >> 3);
  unsigned bx = wg % gx;
  unsigned tmp = wg / gx;
  unsigned by = tmp % gy;
  unsigned bz = tmp / gy;

  const int n0 = bx * 128;
  const int arow0 = bz * aRowsPerZ + by * 128;
  const int crow0 = bz * cRowsPerZ + by * 128;

  f32x4 acc[4][4] = {};

  for (int s = 0; s < S; ++s) {
    const u16* Ab = A + ((size_t)arow0 + s) * (size_t)lda;
    const u16* Bb = Bt + (size_t)s * bShift;
    for (int k0 = 0; k0 < K; k0 += 64) {
#pragma unroll
      for (int c = 0; c < 4; ++c) {
        int chunk = wave * 4 + c;
        gload_lds16(Ab + (size_t)(chunk * 8 + srow) * lda + k0 + scol,
                    Alds + chunk * 512);
      }
#pragma unroll
      for (int c = 0; c < 4; ++c) {
        int chunk = wave * 4 + c;
        gload_lds16(Bb + (size_t)(n0 + chunk * 8 + srow) * K + k0 + scol,
                    Blds + chunk * 512);
      }
      __syncthreads();
#pragma unroll
      for (int kk = 0; kk < 64; kk += 32) {
        bf16x8 af[4], bfr[4];
#pragma unroll
        for (int mt = 0; mt < 4; ++mt)
          af[mt] = *(const bf16x8*)&Alds[(wm * 64 + mt * 16 + l15) * 64 + ((kk + quad * 8) ^ xk)];
#pragma unroll
        for (int nt = 0; nt < 4; ++nt)
          bfr[nt] = *(const bf16x8*)&Blds[(wn * 64 + nt * 16 + l15) * 64 + ((kk + quad * 8) ^ xk)];
#pragma unroll
        for (int mt = 0; mt < 4; ++mt)
#pragma unroll
          for (int nt = 0; nt < 4; ++nt)
            acc[mt][nt] = __builtin_amdgcn_mfma_f32_16x16x32_bf16(af[mt], bfr[nt], acc[mt][nt], 0, 0, 0);
      }
      __syncthreads();
    }
  }

  // ---- epilogue: transpose acc through LDS, vectorized global IO ----
  const int rgrp = tid >> 5;        // 0..7 (8 rows each)
  const int c4 = (tid & 31) * 4;    // local col, 4-wide
  const int gcol = n0 + c4;
  float4 bias4 = make_float4(0.f, 0.f, 0.f, 0.f);
  if constexpr (EPI == 1 || EPI == 2 || EPI == 3) bias4 = *(const float4*)&bias[gcol];

#pragma unroll
  for (int p = 0; p < 2; ++p) {
    if (wm == p) {
#pragma unroll
      for (int mt = 0; mt < 4; ++mt)
#pragma unroll
        for (int nt = 0; nt < 4; ++nt)
#pragma unroll
          for (int r = 0; r < 4; ++r)
            ldsT[mt * 16 + quad * 4 + r][wn * 64 + nt * 16 + l15] = acc[mt][nt][r];
    }
    __syncthreads();
#pragma unroll
    for (int j = 0; j < 8; ++j) {
      int lrow = rgrp * 8 + j;
      size_t grow = (size_t)crow0 + p * 64 + lrow;
      float4 v = *(const float4*)&ldsT[lrow][c4];
      if constexpr (EPI == 0) {
        *(float4*)&C[grow * N + gcol] = v;
      } else if constexpr (EPI == 1) {
        float4 c = *(const float4*)&C[grow * N + gcol];
        c.x += v.x + bias4.x; c.y += v.y + bias4.y;
        c.z += v.z + bias4.z; c.w += v.w + bias4.w;
        *(float4*)&C[grow * N + gcol] = c;
      } else if constexpr (EPI == 2) {
        float t0 = v.x + bias4.x, t1 = v.y + bias4.y, t2 = v.z + bias4.z, t3 = v.w + bias4.w;
        ushort4 o;
        o.x = f2bf(t0 * 0.5f * (1.f + erff(t0 * 0.70710678118f)));
        o.y = f2bf(t1 * 0.5f * (1.f + erff(t1 * 0.70710678118f)));
        o.z = f2bf(t2 * 0.5f * (1.f + erff(t2 * 0.70710678118f)));
        o.w = f2bf(t3 * 0.5f * (1.f + erff(t3 * 0.70710678118f)));
        *(ushort4*)&Cbf[grow * N + gcol] = o;
      } else if constexpr (EPI == 3) {
        float4 c;
        c.x = fmaxf(v.x + bias4.x, 0.f); c.y = fmaxf(v.y + bias4.y, 0.f);
        c.z = fmaxf(v.z + bias4.z, 0.f); c.w = fmaxf(v.w + bias4.w, 0.f);
        *(float4*)&C[grow * N + gcol] = c;
      } else {
        ushort4 o;
        o.x = f2bf(v.x); o.y = f2bf(v.y); o.z = f2bf(v.z); o.w = f2bf(v.w);
        *(ushort4*)&Cbf[grow * N + gcol] = o;
      }
    }
    __syncthreads();
  }
}

// ---------------- small fp32 GEMM (head c1: N=32) ------------------------------------
template <int NT, int EPI>
__launch_bounds__(256)
__global__ void gemm_f32(const float* __restrict__ A, const float* __restrict__ B,
                         float* __restrict__ C, const float* __restrict__ bias,
                         int M, int N, int K) {
  __shared__ __align__(16) float As[16][68];
  __shared__ __align__(16) float Bs[16][NT + 4];
  int tid = threadIdx.x;
  int tx = tid & 15, ty = tid >> 4;
  int n0 = blockIdx.x * NT, m0 = blockIdx.y * 64;
  constexpr int TN = NT / 16;
  float acc[4][TN] = {};
  int arow = tid >> 2, akg = (tid & 3) * 4;
  int bk, bng;
  if (NT == 64) { bk = tid >> 4; bng = (tid & 15) * 4; }
  else          { bk = tid >> 3; bng = (tid & 7) * 4; }
  bool bload = (NT == 64) || (tid < 128);
  const float* Ap = A + (size_t)(m0 + arow) * K + akg;
  const float* Bp = B + (size_t)bk * N + n0 + bng;
  for (int k0 = 0; k0 < K; k0 += 16) {
    float4 av = *(const float4*)(Ap + k0);
    float4 bv = make_float4(0.f, 0.f, 0.f, 0.f);
    if (bload) bv = *(const float4*)(Bp + (size_t)k0 * N);
    __syncthreads();
    As[akg + 0][arow] = av.x; As[akg + 1][arow] = av.y;
    As[akg + 2][arow] = av.z; As[akg + 3][arow] = av.w;
    if (bload) *(float4*)&Bs[bk][bng] = bv;
    __syncthreads();
#pragma unroll
    for (int k = 0; k < 16; ++k) {
      float4 a4 = *(const float4*)&As[k][ty * 4];
      float a[4] = {a4.x, a4.y, a4.z, a4.w};
      float b[TN];
#pragma unroll
      for (int j = 0; j < TN; j++) b[j] = Bs[k][tx * TN + j];
#pragma unroll
      for (int i = 0; i < 4; i++)
#pragma unroll
        for (int j = 0; j < TN; j++) acc[i][j] = fmaf(a[i], b[j], acc[i][j]);
    }
  }
#pragma unroll
  for (int i = 0; i < 4; i++) {
    size_t row = m0 + ty * 4 + i;
    float* Cp = C + row * (size_t)N + n0 + tx * TN;
#pragma unroll
    for (int j = 0; j < TN; j++) {
      float v = acc[i][j];
      if (EPI >= 1) v += bias[n0 + tx * TN + j];
      Cp[j] = v;
    }
  }
}

// ---------------- LayerNorm over last dim (512), bf16 out ----------------------------
__launch_bounds__(256)
__global__ void ln_kernel(const float* __restrict__ h, const float* __restrict__ g,
                          const float* __restrict__ b, u16* __restrict__ u) {
  int row = blockIdx.x * 4 + (threadIdx.x >> 6);
  int lane = threadIdx.x & 63;
  const float* hp = h + (size_t)row * C_DIM + lane * 8;
  float4 a0 = *(const float4*)hp;
  float4 a1 = *(const float4*)(hp + 4);
  float s = a0.x + a0.y + a0.z + a0.w + a1.x + a1.y + a1.z + a1.w;
#pragma unroll
  for (int o = 32; o > 0; o >>= 1) s += __shfl_xor(s, o);
  float mu = s * (1.f / 512.f);
  float d[8] = {a0.x - mu, a0.y - mu, a0.z - mu, a0.w - mu,
                a1.x - mu, a1.y - mu, a1.z - mu, a1.w - mu};
  float q = 0.f;
#pragma unroll
  for (int j = 0; j < 8; ++j) q += d[j] * d[j];
#pragma unroll
  for (int o = 32; o > 0; o >>= 1) q += __shfl_xor(q, o);
  float rs = rsqrtf(q * (1.f / 512.f) + EPS);
  const float* gp = g + lane * 8;
  const float* bp = b + lane * 8;
  float4 g0 = *(const float4*)gp, g1 = *(const float4*)(gp + 4);
  float4 b0 = *(const float4*)bp, b1 = *(const float4*)(bp + 4);
  float gv[8] = {g0.x, g0.y, g0.z, g0.w, g1.x, g1.y, g1.z, g1.w};
  float bv[8] = {b0.x, b0.y, b0.z, b0.w, b1.x, b1.y, b1.z, b1.w};
  ushort4 o0, o1;
  o0.x = f2bf(d[0] * rs * gv[0] + bv[0]);
  o0.y = f2bf(d[1] * rs * gv[1] + bv[1]);
  o0.z = f2bf(d[2] * rs * gv[2] + bv[2]);
  o0.w = f2bf(d[3] * rs * gv[3] + bv[3]);
  o1.x = f2bf(d[4] * rs * gv[4] + bv[4]);
  o1.y = f2bf(d[5] * rs * gv[5] + bv[5]);
  o1.z = f2bf(d[6] * rs * gv[6] + bv[6]);
  o1.w = f2bf(d[7] * rs * gv[7] + bv[7]);
  u16* up = u + (size_t)row * C_DIM + lane * 8;
  *(ushort4*)up = o0;
  *(ushort4*)(up + 4) = o1;
}

// ---------------- MFMA flash attention: block = (head, bn), 8 waves ------------------
__launch_bounds__(512, 2)
__global__ void attn_mfma(const u16* __restrict__ qkv, u16* __restrict__ o) {
  __shared__ u16 Ks[64 * 136];        // [kk][d], pad 136
  __shared__ u32 Vt32[128 * 44];      // [d][kk-pair], pad 44 dwords (=88 u16)
  __shared__ u16 Ps[8][32 * 80];      // per-wave P [m][kk], pad 80

  const int tid = threadIdx.x;
  const int lane = tid & 63, wave = tid >> 6;
  const int quad = lane >> 4, l15 = lane & 15;
  const int hh = blockIdx.x, bl = blockIdx.y;
  const u16* base = qkv + (size_t)bl * T_SEQ * QKV_N;

  bf16x8 qf[2][4];
#pragma unroll
  for (int mi = 0; mi < 2; mi++) {
    int row = wave * 32 + mi * 16 + l15;
    const u16* qp = base + (size_t)row * QKV_N + hh * DHEAD + quad * 8;
#pragma unroll
    for (int k0 = 0; k0 < 4; k0++)
      qf[mi][k0] = *(const bf16x8*)(qp + k0 * 32);
  }

  f32x4 oa[2][8] = {};
  float mrow[2][4], lrow[2][4];
#pragma unroll
  for (int mi = 0; mi < 2; mi++)
#pragma unroll
    for (int r = 0; r < 4; r++) { mrow[mi][r] = -1e30f; lrow[mi][r] = 0.f; }

  for (int kt = 0; kt < 4; kt++) {
    __syncthreads();
    {
      int kk = tid >> 3, dbase = (tid & 7) * 16;
      const u16* kp = base + (size_t)(kt * 64 + kk) * QKV_N + C_DIM + hh * DHEAD + dbase;
      uint4 a = *(const uint4*)kp;
      uint4 b = *(const uint4*)(kp + 8);
      *(uint4*)&Ks[kk * 136 + dbase] = a;
      *(uint4*)&Ks[kk * 136 + dbase + 8] = b;
    }
    {
      int kkp = tid >> 4, dbase = (tid & 15) * 8;
      const u16* vp = base + (size_t)(kt * 64 + kkp * 2) * QKV_N + 2 * C_DIM + hh * DHEAD + dbase;
      union { uint4 u; u16 h[8]; } va, vb;
      va.u = *(const uint4*)vp;
      vb.u = *(const uint4*)(vp + QKV_N);
#pragma unroll
      for (int j = 0; j < 8; j++)
        Vt32[(dbase + j) * 44 + kkp] = (u32)va.h[j] | ((u32)vb.h[j] << 16);
    }
    __syncthreads();

    f32x4 sa[2][4] = {};
#pragma unroll
    for (int k0 = 0; k0 < 4; k0++) {
      bf16x8 kf[4];
#pragma unroll
      for (int ni = 0; ni < 4; ni++)
        kf[ni] = *(const bf16x8*)&Ks[(ni * 16 + l15) * 136 + k0 * 32 + quad * 8];
      __builtin_amdgcn_s_setprio(1);
#pragma unroll
      for (int mi = 0; mi < 2; mi++)
#pragma unroll
        for (int ni = 0; ni < 4; ni++)
          sa[mi][ni] = __builtin_amdgcn_mfma_f32_16x16x32_bf16(qf[mi][k0], kf[ni], sa[mi][ni], 0, 0, 0);
      __builtin_amdgcn_s_setprio(0);
    }

#pragma unroll
    for (int mi = 0; mi < 2; mi++) {
#pragma unroll
      for (int r = 0; r < 4; r++) {
        float mx = fmaxf(fmaxf(sa[mi][0][r], sa[mi][1][r]), fmaxf(sa[mi][2][r], sa[mi][3][r]));
        mx = fmaxf(mx, __shfl_xor(mx, 1));
        mx = fmaxf(mx, __shfl_xor(mx, 2));
        mx = fmaxf(mx, __shfl_xor(mx, 4));
        mx = fmaxf(mx, __shfl_xor(mx, 8));
        mx *= ATT_SCALE;
        float mnew = fmaxf(mrow[mi][r], mx);
        float alpha = __expf(mrow[mi][r] - mnew);
        mrow[mi][r] = mnew;
        float rs = 0.f;
#pragma unroll
        for (int ni = 0; ni < 4; ni++) {
          float p = __expf(sa[mi][ni][r] * ATT_SCALE - mnew);
          rs += p;
          Ps[wave][(mi * 16 + quad * 4 + r) * 80 + ni * 16 + l15] = f2bf(p);
        }
        rs += __shfl_xor(rs, 1);
        rs += __shfl_xor(rs, 2);
        rs += __shfl_xor(rs, 4);
        rs += __shfl_xor(rs, 8);
        lrow[mi][r] = lrow[mi][r] * alpha + rs;
#pragma unroll
        for (int nj = 0; nj < 8; nj++) oa[mi][nj][r] *= alpha;
      }
    }

#pragma unroll
    for (int k0 = 0; k0 < 2; k0++) {
      bf16x8 pf[2];
#pragma unroll
      for (int mi = 0; mi < 2; mi++)
        pf[mi] = *(const bf16x8*)&Ps[wave][(mi * 16 + l15) * 80 + k0 * 32 + quad * 8];
      __builtin_amdgcn_s_setprio(1);
#pragma unroll
      for (int nj = 0; nj < 8; nj++) {
        bf16x8 vf = *(const bf16x8*)&Vt32[(nj * 16 + l15) * 44 + k0 * 16 + quad * 4];
#pragma unroll
        for (int mi = 0; mi < 2; mi++)
          oa[mi][nj] = __builtin_amdgcn_mfma_f32_16x16x32_bf16(pf[mi], vf, oa[mi][nj], 0, 0, 0);
      }
      __builtin_amdgcn_s_setprio(0);
    }
  }

#pragma unroll
  for (int mi = 0; mi < 2; mi++) {
#pragma unroll
    for (int r = 0; r < 4; r++) {
      int row = wave * 32 + mi * 16 + quad * 4 + r;
      float inv = 1.f / lrow[mi][r];
      u16* op = o + ((size_t)bl * T_SEQ + row) * C_DIM + hh * DHEAD + l15;
#pragma unroll
      for (int nj = 0; nj < 8; nj++)
        op[nj * 16] = f2bf(oa[mi][nj][r] * inv);
    }
  }
}

// ---------------- NormalHead ---------------------------------------------------------
__global__ void head_kernel(const float* __restrict__ x1,
                            const float* __restrict__ bn1g, const float* __restrict__ bn1b,
                            const float* __restrict__ bn1rm, const float* __restrict__ bn1rv,
                            const float* __restrict__ c2W, const float* __restrict__ c2b,
                            const float* __restrict__ bn2g, const float* __restrict__ bn2b,
                            const float* __restrict__ bn2rm, const float* __restrict__ bn2rv,
                            const float* __restrict__ c3W, const float* __restrict__ c3b,
                            float* __restrict__ d1a, float* __restrict__ d2a, float* __restrict__ sca) {
  int r = blockIdx.x * 256 + threadIdx.x;
  if (r >= BN_TOT * T_SEQ) return;
  const float* xp = x1 + (size_t)r * 32;
  float y[32];
  float d1 = 0.f;
#pragma unroll
  for (int oc = 0; oc < 32; oc++) {
    float v = xp[oc];
    float dm = v - bn1rm[oc];
    d1 += dm * dm / bn1rv[oc];
    float t = dm * rsqrtf(bn1rv[oc] + EPS) * bn1g[oc] + bn1b[oc];
    y[oc] = fmaxf(t, 0.f);
  }
  float d2 = 0.f, sacc = 0.f;
#pragma unroll
  for (int o2 = 0; o2 < 16; o2++) {
    float s2 = 0.f;
#pragma unroll
    for (int oc = 0; oc < 32; oc++) s2 = fmaf(y[oc], c2W[o2 * 32 + oc], s2);
    s2 += c2b[o2];
    float dm = s2 - bn2rm[o2];
    d2 += dm * dm / bn2rv[o2];
    float t = dm * rsqrtf(bn2rv[o2] + EPS) * bn2g[o2] + bn2b[o2];
    t = fmaxf(t, 0.f);
    sacc = fmaf(t, c3W[o2], sacc);
  }
  float sc = 1.f / (1.f + expf(-(sacc + c3b[0])));
  d1a[r] = sqrtf(d1);
  d2a[r] = sqrtf(d2);
  sca[r] = sc;
}

__global__ void reduce_kernel(const float* __restrict__ d1a, const float* __restrict__ d2a,
                              const float* __restrict__ sca, float* __restrict__ out) {
  int idx = blockIdx.x * 256 + threadIdx.x;
  if (idx >= 32 * T_SEQ) return;
  int b = idx >> 8, t = idx & 255;
  float s1 = 0.f, s2 = 0.f, ss = 0.f;
  for (int n = 0; n < 10; n++) {
    int r = (b * 10 + n) * T_SEQ + t;
    s1 += d1a[r];
    s2 += d2a[r];
    ss += sca[r];
  }
  out[idx] = (s1 + s2) * ss * 0.01f;
}

extern "C" void kernel_launch(void* const* d_in, const int* in_sizes, int n_in,
                              void* d_out, int out_size, void* d_ws, size_t ws_size,
                              hipStream_t stream) {
  const float* x     = (const float*)d_in[0];
  const float* Wemb  = (const float*)d_in[1];
  const float* bemb  = (const float*)d_in[2];
  const float* ln1g  = (const float*)d_in[3];
  const float* ln1b  = (const float*)d_in[4];
  const float* Wqkv  = (const float*)d_in[5];
  const float* Wo    = (const float*)d_in[6];
  const float* bo    = (const float*)d_in[7];
  const float* ln2g  = (const float*)d_in[8];
  const float* ln2b  = (const float*)d_in[9];
  const float* W1    = (const float*)d_in[10];
  const float* b1    = (const float*)d_in[11];
  const float* W2    = (const float*)d_in[12];
  const float* b2    = (const float*)d_in[13];
  const float* c1W   = (const float*)d_in[14];
  const float* c1b   = (const float*)d_in[15];
  const float* bn1g  = (const float*)d_in[16];
  const float* bn1b  = (const float*)d_in[17];
  const float* bn1rm = (const float*)d_in[18];
  const float* bn1rv = (const float*)d_in[19];
  const float* c2W   = (const float*)d_in[20];
  const float* c2b   = (const float*)d_in[21];
  const float* bn2g  = (const float*)d_in[22];
  const float* bn2b  = (const float*)d_in[23];
  const float* bn2rm = (const float*)d_in[24];
  const float* bn2rv = (const float*)d_in[25];
  const float* c3W   = (const float*)d_in[26];
  const float* c3b   = (const float*)d_in[27];

  char* w = (char*)d_ws;
  size_t off = 0;
  auto alloc = [&](size_t nbytes) {
    void* p = (void*)(w + off);
    off += (nbytes + 255) & ~(size_t)255;
    return p;
  };
  float* h      = (float*)alloc((size_t)BN_TOT * T_SEQ * C_DIM * 4);   // 168 MB
  u16*   u_bf   = (u16*)  alloc((size_t)BN_TOT * T_SEQ * C_DIM * 2);   // 84 MB
  u16*   scratch= (u16*)  alloc((size_t)BN_TOT * T_SEQ * QKV_N * 2);   // 252 MB: xpad / qkv / mlp-mid
  u16*   Wct    = (u16*)  alloc((size_t)3 * C_DIM * D_DIM * 2);
  u16*   Wqkvt  = (u16*)  alloc((size_t)2 * QKV_N * C_DIM * 2);
  u16*   Wot    = (u16*)  alloc((size_t)2 * C_DIM * C_DIM * 2);
  u16*   W1t    = (u16*)  alloc((size_t)2 * C_DIM * C_DIM * 2);
  u16*   W2t    = (u16*)  alloc((size_t)2 * C_DIM * C_DIM * 2);
  float* Wc1t   = (float*)alloc((size_t)C_DIM * 32 * 4);
  float* x1     = (float*)alloc((size_t)BN_TOT * T_SEQ * 32 * 4);
  float* d1a    = (float*)alloc((size_t)BN_TOT * T_SEQ * 4);
  float* d2a    = (float*)alloc((size_t)BN_TOT * T_SEQ * 4);
  float* sca    = (float*)alloc((size_t)BN_TOT * T_SEQ * 4);
  u16* xpad  = scratch;   // 169 MB, dead after conv
  u16* qkvbf = scratch;   // 252 MB, per layer
  u16* midbf = scratch;   // 84 MB mlp mid (qkv dead by then)

  {
    size_t nx4 = (size_t)BN_TOT * 258 * 1024 / 4;
    convert_x<<<(unsigned)((nx4 + 255) / 256), 256, 0, stream>>>(x, xpad);
  }
  prep_wct<<<(3 * C_DIM * D_DIM + 255) / 256, 256, 0, stream>>>(Wemb, Wct);
  for (int l = 0; l < 2; ++l) {
    transpose_w<<<dim3(QKV_N / 32, C_DIM / 32), 256, 0, stream>>>(
        Wqkv + (size_t)l * C_DIM * QKV_N, Wqkvt + (size_t)l * QKV_N * C_DIM, C_DIM, QKV_N);
    transpose_w<<<dim3(C_DIM / 32, C_DIM / 32), 256, 0, stream>>>(
        Wo + (size_t)l * C_DIM * C_DIM, Wot + (size_t)l * C_DIM * C_DIM, C_DIM, C_DIM);
    transpose_w<<<dim3(C_DIM / 32, C_DIM / 32), 256, 0, stream>>>(
        W1 + (size_t)l * C_DIM * C_DIM, W1t + (size_t)l * C_DIM * C_DIM, C_DIM, C_DIM);
    transpose_w<<<dim3(C_DIM / 32, C_DIM / 32), 256, 0, stream>>>(
        W2 + (size_t)l * C_DIM * C_DIM, W2t + (size_t)l * C_DIM * C_DIM, C_DIM, C_DIM);
  }
  prep_c1t<<<(C_DIM * 32 + 255) / 256, 256, 0, stream>>>(c1W, Wc1t);

  // conv as 3 shifted GEMMs over padded bf16 x, relu+bias -> h fp32
  gemm_mfma<3, 3><<<dim3(C_DIM / 128, 2, BN_TOT), 256, 0, stream>>>(
      xpad, 1024, 258, Wct, (size_t)C_DIM * D_DIM, D_DIM, h, nullptr, bemb, C_DIM, 256);

  for (int l = 0; l < 2; ++l) {
    ln_kernel<<<BN_TOT * T_SEQ / 4, 256, 0, stream>>>(h, ln1g + l * C_DIM, ln1b + l * C_DIM, u_bf);
    gemm_mfma<1, 4><<<dim3(QKV_N / 128, 640, 1), 256, 0, stream>>>(
        u_bf, C_DIM, 0, Wqkvt + (size_t)l * QKV_N * C_DIM, 0, C_DIM,
        nullptr, qkvbf, nullptr, QKV_N, 0);
    attn_mfma<<<dim3(NHEAD, BN_TOT), 512, 0, stream>>>(qkvbf, u_bf);
    gemm_mfma<1, 1><<<dim3(C_DIM / 128, 640, 1), 256, 0, stream>>>(
        u_bf, C_DIM, 0, Wot + (size_t)l * C_DIM * C_DIM, 0, C_DIM, h, nullptr, bo + l * C_DIM, C_DIM, 0);
    ln_kernel<<<BN_TOT * T_SEQ / 4, 256, 0, stream>>>(h, ln2g + l * C_DIM, ln2b + l * C_DIM, u_bf);
    gemm_mfma<1, 2><<<dim3(C_DIM / 128, 640, 1), 256, 0, stream>>>(
        u_bf, C_DIM, 0, W1t + (size_t)l * C_DIM * C_DIM, 0, C_DIM, nullptr, midbf, b1 + l * C_DIM, C_DIM, 0);
    gemm_mfma<1, 1><<<dim3(C_DIM / 128, 640, 1), 256, 0, stream>>>(
        midbf, C_DIM, 0, W2t + (size_t)l * C_DIM * C_DIM, 0, C_DIM, h, nullptr, b2 + l * C_DIM, C_DIM, 0);
  }

  gemm_f32<32, 1><<<dim3(1, 81920 / 64), 256, 0, stream>>>(h, Wc1t, x1, c1b, 81920, 32, C_DIM);
  head_kernel<<<(BN_TOT * T_SEQ + 255) / 256, 256, 0, stream>>>(
      x1, bn1g, bn1b, bn1rm, bn1rv, c2W, c2b, bn2g, bn2b, bn2rm, bn2rv, c3W, c3b, d1a, d2a, sca);
  reduce_kernel<<<32, 256, 0, stream>>>(d1a, d2a, sca, (float*)d_out);
}

// Round 4
// 2380.740 us; speedup vs baseline: 1.2125x; 1.0334x over previous
//
#include <hip/hip_runtime.h>
#include <math.h>

#define T_SEQ 256
#define C_DIM 512
#define D_DIM 1024
#define BN_TOT 320
#define NHEAD 4
#define DHEAD 128
#define QKV_N 1536
#define EPS 1e-5f
#define ATT_SCALE 0.08838834764831845f

typedef unsigned short u16;
typedef unsigned int u32;
typedef __attribute__((ext_vector_type(8))) short bf16x8;
typedef __attribute__((ext_vector_type(4))) float f32x4;

__device__ __forceinline__ u16 f2bf(float f) {
  union { float f; u32 u; } v; v.f = f;
  u32 r = v.u + 0x7fffu + ((v.u >> 16) & 1u);
  return (u16)(r >> 16);
}

__device__ __forceinline__ void gload_lds16(const u16* g, u16* l) {
  __builtin_amdgcn_global_load_lds((const __attribute__((address_space(1))) u32*)g,
                                   (__attribute__((address_space(3))) u32*)l, 16, 0, 0);
}

// ---------------- prep kernels -------------------------------------------------------
__global__ void convert_x(const float* __restrict__ x, u16* __restrict__ xpad) {
  size_t i4 = ((size_t)blockIdx.x * 256 + threadIdx.x) * 4;
  if (i4 >= (size_t)BN_TOT * 258 * 1024) return;
  size_t row = i4 >> 10; int col = (int)(i4 & 1023);
  int bn = (int)(row / 258), tr = (int)(row % 258);
  ushort4 o;
  if (tr == 0 || tr == 257) {
    o.x = 0; o.y = 0; o.z = 0; o.w = 0;
  } else {
    float4 v = *(const float4*)&x[((size_t)bn * 256 + tr - 1) * 1024 + col];
    o.x = f2bf(v.x); o.y = f2bf(v.y); o.z = f2bf(v.z); o.w = f2bf(v.w);
  }
  *(ushort4*)&xpad[i4] = o;
}

__global__ void prep_wct(const float* __restrict__ Wemb, u16* __restrict__ Wct) {
  int idx = blockIdx.x * 256 + threadIdx.x;
  if (idx >= 3 * C_DIM * D_DIM) return;
  int d = idx & 1023;
  int c = (idx >> 10) & 511;
  int s = idx >> 19;
  Wct[idx] = f2bf(Wemb[(c * D_DIM + d) * 3 + s]);
}

// tiled transpose: src [K][N] fp32 -> dst [N][K] bf16. 32x32 tiles, coalesced both sides.
__launch_bounds__(256)
__global__ void transpose_w(const float* __restrict__ src, u16* __restrict__ dst, int K, int N) {
  __shared__ float t[32][33];
  int tid = threadIdx.x;
  int n0 = blockIdx.x * 32, k0 = blockIdx.y * 32;
  int r = tid >> 3, c4 = (tid & 7) * 4;
  float4 v = *(const float4*)&src[(size_t)(k0 + r) * N + n0 + c4];
  t[r][c4 + 0] = v.x; t[r][c4 + 1] = v.y; t[r][c4 + 2] = v.z; t[r][c4 + 3] = v.w;
  __syncthreads();
  ushort4 o;
  o.x = f2bf(t[c4 + 0][r]);
  o.y = f2bf(t[c4 + 1][r]);
  o.z = f2bf(t[c4 + 2][r]);
  o.w = f2bf(t[c4 + 3][r]);
  *(ushort4*)&dst[(size_t)(n0 + r) * K + k0 + c4] = o;
}

__global__ void prep_c1t(const float* __restrict__ c1W, float* __restrict__ Wt) {
  int idx = blockIdx.x * 256 + threadIdx.x;
  if (idx >= C_DIM * 32) return;
  int n = idx & 31;
  int k = idx >> 5;
  Wt[idx] = c1W[n * C_DIM + k];
}

// ---------------- bf16 MFMA GEMM -----------------------------------------------------
// EPI: 0 = store fp32, 1 = C += acc+bias (fp32), 2 = Cbf = bf16(gelu(acc+bias)),
//      3 = C = relu(acc+bias) fp32, 4 = Cbf = bf16(acc)
// T2 LDS swizzle (rule #21): linear gload_lds dest, pre-swizzled global source col,
// matching XOR on ds_read.
// T3-minimum 2-phase pipeline: double-buffered LDS; STAGE(t+1) issued BEFORE
// compute(t); one vmcnt(0)+raw s_barrier per tile (HBM latency hides under
// ds_read+MFMA). sched_barrier(0) fences pin the schedule (rule #18).
template <int S, int EPI>
__launch_bounds__(256)
__global__ void gemm_mfma(const u16* __restrict__ A, int lda, int aRowsPerZ,
                          const u16* __restrict__ Bt, size_t bShift, int K,
                          float* __restrict__ C, u16* __restrict__ Cbf,
                          const float* __restrict__ bias, int N, int cRowsPerZ) {
  __shared__ __align__(16) u16 lds_all[2 * 16384];   // 64 KB: 2 x (A 16KB + B 16KB)
  float (*ldsT)[132] = (float (*)[132])lds_all;      // epilogue alias (33 KB)

  const int tid = threadIdx.x;
  const int lane = tid & 63;
  const int wave = tid >> 6;
  const int wm = wave >> 1, wn = wave & 1;
  const int quad = lane >> 4;
  const int l15 = lane & 15;
  const int srow = lane >> 3;                    // 0..7 within staging group
  const int scol = ((lane & 7) ^ srow) * 8;      // swizzled source col (u16)
  const int xk = (l15 & 7) * 8;                  // read-side XOR (u16)

  // T1: XCD-aware bijective chunked swizzle (nwg % 8 == 0 for all our launches).
  unsigned gx = gridDim.x, gy = gridDim.y, gz = gridDim.z;
  unsigned orig = (blockIdx.z * gy + blockIdx.y) * gx + blockIdx.x;
  unsigned nwg = gx * gy * gz;
  unsigned wg = orig;
  if ((nwg & 7u) == 0u) wg = (orig & 7u) * (nwg >> 3) + (orig >> 3);
  unsigned bx = wg % gx;
  unsigned tmp = wg / gx;
  unsigned by = tmp % gy;
  unsigned bz = tmp / gy;

  const int n0 = bx * 128;
  const int arow0 = bz * aRowsPerZ + by * 128;
  const int crow0 = bz * cRowsPerZ + by * 128;

  const int ksteps = K >> 6;
  const int nt = S * ksteps;

  f32x4 acc[4][4] = {};

  auto stage = [&](int buf, int t) {
    int s = (S == 1) ? 0 : (t / ksteps);
    int k0 = (S == 1) ? (t << 6) : ((t - s * ksteps) << 6);
    const u16* Ab = A + ((size_t)arow0 + s) * (size_t)lda + k0;
    const u16* Bb = Bt + (size_t)s * bShift + k0;
    u16* Al = lds_all + buf * 16384;
    u16* Bl = Al + 8192;
#pragma unroll
    for (int c = 0; c < 4; ++c) {
      int chunk = wave * 4 + c;
      gload_lds16(Ab + (size_t)(chunk * 8 + srow) * lda + scol, Al + chunk * 512);
    }
#pragma unroll
    for (int c = 0; c < 4; ++c) {
      int chunk = wave * 4 + c;
      gload_lds16(Bb + (size_t)(n0 + chunk * 8 + srow) * K + scol, Bl + chunk * 512);
    }
  };

  auto compute = [&](int buf) {
    const u16* Al = lds_all + buf * 16384;
    const u16* Bl = Al + 8192;
#pragma unroll
    for (int kk = 0; kk < 64; kk += 32) {
      bf16x8 af[4], bfr[4];
#pragma unroll
      for (int mt = 0; mt < 4; ++mt)
        af[mt] = *(const bf16x8*)&Al[(wm * 64 + mt * 16 + l15) * 64 + ((kk + quad * 8) ^ xk)];
#pragma unroll
      for (int nt2 = 0; nt2 < 4; ++nt2)
        bfr[nt2] = *(const bf16x8*)&Bl[(wn * 64 + nt2 * 16 + l15) * 64 + ((kk + quad * 8) ^ xk)];
#pragma unroll
      for (int mt = 0; mt < 4; ++mt)
#pragma unroll
        for (int nt2 = 0; nt2 < 4; ++nt2)
          acc[mt][nt2] = __builtin_amdgcn_mfma_f32_16x16x32_bf16(af[mt], bfr[nt2], acc[mt][nt2], 0, 0, 0);
    }
  };

  // prologue
  stage(0, 0);
  asm volatile("s_waitcnt vmcnt(0)" ::: "memory");
  __builtin_amdgcn_s_barrier();
  __builtin_amdgcn_sched_barrier(0);

  int cur = 0;
  for (int t = 0; t < nt - 1; ++t) {
    stage(cur ^ 1, t + 1);         // issue next-tile loads (latency hides under compute)
    compute(cur);
    __builtin_amdgcn_sched_barrier(0);
    asm volatile("s_waitcnt vmcnt(0)" ::: "memory");
    __builtin_amdgcn_s_barrier();
    __builtin_amdgcn_sched_barrier(0);
    cur ^= 1;
  }
  compute(cur);                    // last tile, nothing to prefetch

  __syncthreads();                 // full drain before LDS reuse

  // ---- epilogue: transpose acc through LDS, vectorized global IO ----
  const int rgrp = tid >> 5;        // 0..7 (8 rows each)
  const int c4 = (tid & 31) * 4;    // local col, 4-wide
  const int gcol = n0 + c4;
  float4 bias4 = make_float4(0.f, 0.f, 0.f, 0.f);
  if constexpr (EPI == 1 || EPI == 2 || EPI == 3) bias4 = *(const float4*)&bias[gcol];

#pragma unroll
  for (int p = 0; p < 2; ++p) {
    if (wm == p) {
#pragma unroll
      for (int mt = 0; mt < 4; ++mt)
#pragma unroll
        for (int nt2 = 0; nt2 < 4; ++nt2)
#pragma unroll
          for (int r = 0; r < 4; ++r)
            ldsT[mt * 16 + quad * 4 + r][wn * 64 + nt2 * 16 + l15] = acc[mt][nt2][r];
    }
    __syncthreads();
#pragma unroll
    for (int j = 0; j < 8; ++j) {
      int lrow = rgrp * 8 + j;
      size_t grow = (size_t)crow0 + p * 64 + lrow;
      float4 v = *(const float4*)&ldsT[lrow][c4];
      if constexpr (EPI == 0) {
        *(float4*)&C[grow * N + gcol] = v;
      } else if constexpr (EPI == 1) {
        float4 c = *(const float4*)&C[grow * N + gcol];
        c.x += v.x + bias4.x; c.y += v.y + bias4.y;
        c.z += v.z + bias4.z; c.w += v.w + bias4.w;
        *(float4*)&C[grow * N + gcol] = c;
      } else if constexpr (EPI == 2) {
        float t0 = v.x + bias4.x, t1 = v.y + bias4.y, t2 = v.z + bias4.z, t3 = v.w + bias4.w;
        ushort4 o;
        o.x = f2bf(t0 * 0.5f * (1.f + erff(t0 * 0.70710678118f)));
        o.y = f2bf(t1 * 0.5f * (1.f + erff(t1 * 0.70710678118f)));
        o.z = f2bf(t2 * 0.5f * (1.f + erff(t2 * 0.70710678118f)));
        o.w = f2bf(t3 * 0.5f * (1.f + erff(t3 * 0.70710678118f)));
        *(ushort4*)&Cbf[grow * N + gcol] = o;
      } else if constexpr (EPI == 3) {
        float4 c;
        c.x = fmaxf(v.x + bias4.x, 0.f); c.y = fmaxf(v.y + bias4.y, 0.f);
        c.z = fmaxf(v.z + bias4.z, 0.f); c.w = fmaxf(v.w + bias4.w, 0.f);
        *(float4*)&C[grow * N + gcol] = c;
      } else {
        ushort4 o;
        o.x = f2bf(v.x); o.y = f2bf(v.y); o.z = f2bf(v.z); o.w = f2bf(v.w);
        *(ushort4*)&Cbf[grow * N + gcol] = o;
      }
    }
    __syncthreads();
  }
}

// ---------------- small fp32 GEMM (head c1: N=32) ------------------------------------
template <int NT, int EPI>
__launch_bounds__(256)
__global__ void gemm_f32(const float* __restrict__ A, const float* __restrict__ B,
                         float* __restrict__ C, const float* __restrict__ bias,
                         int M, int N, int K) {
  __shared__ __align__(16) float As[16][68];
  __shared__ __align__(16) float Bs[16][NT + 4];
  int tid = threadIdx.x;
  int tx = tid & 15, ty = tid >> 4;
  int n0 = blockIdx.x * NT, m0 = blockIdx.y * 64;
  constexpr int TN = NT / 16;
  float acc[4][TN] = {};
  int arow = tid >> 2, akg = (tid & 3) * 4;
  int bk, bng;
  if (NT == 64) { bk = tid >> 4; bng = (tid & 15) * 4; }
  else          { bk = tid >> 3; bng = (tid & 7) * 4; }
  bool bload = (NT == 64) || (tid < 128);
  const float* Ap = A + (size_t)(m0 + arow) * K + akg;
  const float* Bp = B + (size_t)bk * N + n0 + bng;
  for (int k0 = 0; k0 < K; k0 += 16) {
    float4 av = *(const float4*)(Ap + k0);
    float4 bv = make_float4(0.f, 0.f, 0.f, 0.f);
    if (bload) bv = *(const float4*)(Bp + (size_t)k0 * N);
    __syncthreads();
    As[akg + 0][arow] = av.x; As[akg + 1][arow] = av.y;
    As[akg + 2][arow] = av.z; As[akg + 3][arow] = av.w;
    if (bload) *(float4*)&Bs[bk][bng] = bv;
    __syncthreads();
#pragma unroll
    for (int k = 0; k < 16; ++k) {
      float4 a4 = *(const float4*)&As[k][ty * 4];
      float a[4] = {a4.x, a4.y, a4.z, a4.w};
      float b[TN];
#pragma unroll
      for (int j = 0; j < TN; j++) b[j] = Bs[k][tx * TN + j];
#pragma unroll
      for (int i = 0; i < 4; i++)
#pragma unroll
        for (int j = 0; j < TN; j++) acc[i][j] = fmaf(a[i], b[j], acc[i][j]);
    }
  }
#pragma unroll
  for (int i = 0; i < 4; i++) {
    size_t row = m0 + ty * 4 + i;
    float* Cp = C + row * (size_t)N + n0 + tx * TN;
#pragma unroll
    for (int j = 0; j < TN; j++) {
      float v = acc[i][j];
      if (EPI >= 1) v += bias[n0 + tx * TN + j];
      Cp[j] = v;
    }
  }
}

// ---------------- LayerNorm over last dim (512), bf16 out ----------------------------
__launch_bounds__(256)
__global__ void ln_kernel(const float* __restrict__ h, const float* __restrict__ g,
                          const float* __restrict__ b, u16* __restrict__ u) {
  int row = blockIdx.x * 4 + (threadIdx.x >> 6);
  int lane = threadIdx.x & 63;
  const float* hp = h + (size_t)row * C_DIM + lane * 8;
  float4 a0 = *(const float4*)hp;
  float4 a1 = *(const float4*)(hp + 4);
  float s = a0.x + a0.y + a0.z + a0.w + a1.x + a1.y + a1.z + a1.w;
#pragma unroll
  for (int o = 32; o > 0; o >>= 1) s += __shfl_xor(s, o);
  float mu = s * (1.f / 512.f);
  float d[8] = {a0.x - mu, a0.y - mu, a0.z - mu, a0.w - mu,
                a1.x - mu, a1.y - mu, a1.z - mu, a1.w - mu};
  float q = 0.f;
#pragma unroll
  for (int j = 0; j < 8; ++j) q += d[j] * d[j];
#pragma unroll
  for (int o = 32; o > 0; o >>= 1) q += __shfl_xor(q, o);
  float rs = rsqrtf(q * (1.f / 512.f) + EPS);
  const float* gp = g + lane * 8;
  const float* bp = b + lane * 8;
  float4 g0 = *(const float4*)gp, g1 = *(const float4*)(gp + 4);
  float4 b0 = *(const float4*)bp, b1 = *(const float4*)(bp + 4);
  float gv[8] = {g0.x, g0.y, g0.z, g0.w, g1.x, g1.y, g1.z, g1.w};
  float bv[8] = {b0.x, b0.y, b0.z, b0.w, b1.x, b1.y, b1.z, b1.w};
  ushort4 o0, o1;
  o0.x = f2bf(d[0] * rs * gv[0] + bv[0]);
  o0.y = f2bf(d[1] * rs * gv[1] + bv[1]);
  o0.z = f2bf(d[2] * rs * gv[2] + bv[2]);
  o0.w = f2bf(d[3] * rs * gv[3] + bv[3]);
  o1.x = f2bf(d[4] * rs * gv[4] + bv[4]);
  o1.y = f2bf(d[5] * rs * gv[5] + bv[5]);
  o1.z = f2bf(d[6] * rs * gv[6] + bv[6]);
  o1.w = f2bf(d[7] * rs * gv[7] + bv[7]);
  u16* up = u + (size_t)row * C_DIM + lane * 8;
  *(ushort4*)up = o0;
  *(ushort4*)(up + 4) = o1;
}

// ---------------- MFMA flash attention: block = (head, bn), 8 waves ------------------
__launch_bounds__(512, 2)
__global__ void attn_mfma(const u16* __restrict__ qkv, u16* __restrict__ o) {
  __shared__ u16 Ks[64 * 136];        // [kk][d], pad 136
  __shared__ u32 Vt32[128 * 44];      // [d][kk-pair], pad 44 dwords (=88 u16)
  __shared__ u16 Ps[8][32 * 80];      // per-wave P [m][kk], pad 80

  const int tid = threadIdx.x;
  const int lane = tid & 63, wave = tid >> 6;
  const int quad = lane >> 4, l15 = lane & 15;
  const int hh = blockIdx.x, bl = blockIdx.y;
  const u16* base = qkv + (size_t)bl * T_SEQ * QKV_N;

  bf16x8 qf[2][4];
#pragma unroll
  for (int mi = 0; mi < 2; mi++) {
    int row = wave * 32 + mi * 16 + l15;
    const u16* qp = base + (size_t)row * QKV_N + hh * DHEAD + quad * 8;
#pragma unroll
    for (int k0 = 0; k0 < 4; k0++)
      qf[mi][k0] = *(const bf16x8*)(qp + k0 * 32);
  }

  f32x4 oa[2][8] = {};
  float mrow[2][4], lrow[2][4];
#pragma unroll
  for (int mi = 0; mi < 2; mi++)
#pragma unroll
    for (int r = 0; r < 4; r++) { mrow[mi][r] = -1e30f; lrow[mi][r] = 0.f; }

  for (int kt = 0; kt < 4; kt++) {
    __syncthreads();
    {
      int kk = tid >> 3, dbase = (tid & 7) * 16;
      const u16* kp = base + (size_t)(kt * 64 + kk) * QKV_N + C_DIM + hh * DHEAD + dbase;
      uint4 a = *(const uint4*)kp;
      uint4 b = *(const uint4*)(kp + 8);
      *(uint4*)&Ks[kk * 136 + dbase] = a;
      *(uint4*)&Ks[kk * 136 + dbase + 8] = b;
    }
    {
      int kkp = tid >> 4, dbase = (tid & 15) * 8;
      const u16* vp = base + (size_t)(kt * 64 + kkp * 2) * QKV_N + 2 * C_DIM + hh * DHEAD + dbase;
      union { uint4 u; u16 h[8]; } va, vb;
      va.u = *(const uint4*)vp;
      vb.u = *(const uint4*)(vp + QKV_N);
#pragma unroll
      for (int j = 0; j < 8; j++)
        Vt32[(dbase + j) * 44 + kkp] = (u32)va.h[j] | ((u32)vb.h[j] << 16);
    }
    __syncthreads();

    f32x4 sa[2][4] = {};
#pragma unroll
    for (int k0 = 0; k0 < 4; k0++) {
      bf16x8 kf[4];
#pragma unroll
      for (int ni = 0; ni < 4; ni++)
        kf[ni] = *(const bf16x8*)&Ks[(ni * 16 + l15) * 136 + k0 * 32 + quad * 8];
      __builtin_amdgcn_s_setprio(1);
#pragma unroll
      for (int mi = 0; mi < 2; mi++)
#pragma unroll
        for (int ni = 0; ni < 4; ni++)
          sa[mi][ni] = __builtin_amdgcn_mfma_f32_16x16x32_bf16(qf[mi][k0], kf[ni], sa[mi][ni], 0, 0, 0);
      __builtin_amdgcn_s_setprio(0);
    }

#pragma unroll
    for (int mi = 0; mi < 2; mi++) {
#pragma unroll
      for (int r = 0; r < 4; r++) {
        float mx = fmaxf(fmaxf(sa[mi][0][r], sa[mi][1][r]), fmaxf(sa[mi][2][r], sa[mi][3][r]));
        mx = fmaxf(mx, __shfl_xor(mx, 1));
        mx = fmaxf(mx, __shfl_xor(mx, 2));
        mx = fmaxf(mx, __shfl_xor(mx, 4));
        mx = fmaxf(mx, __shfl_xor(mx, 8));
        mx *= ATT_SCALE;
        float mnew = fmaxf(mrow[mi][r], mx);
        float alpha = __expf(mrow[mi][r] - mnew);
        mrow[mi][r] = mnew;
        float rs = 0.f;
#pragma unroll
        for (int ni = 0; ni < 4; ni++) {
          float p = __expf(sa[mi][ni][r] * ATT_SCALE - mnew);
          rs += p;
          Ps[wave][(mi * 16 + quad * 4 + r) * 80 + ni * 16 + l15] = f2bf(p);
        }
        rs += __shfl_xor(rs, 1);
        rs += __shfl_xor(rs, 2);
        rs += __shfl_xor(rs, 4);
        rs += __shfl_xor(rs, 8);
        lrow[mi][r] = lrow[mi][r] * alpha + rs;
#pragma unroll
        for (int nj = 0; nj < 8; nj++) oa[mi][nj][r] *= alpha;
      }
    }

#pragma unroll
    for (int k0 = 0; k0 < 2; k0++) {
      bf16x8 pf[2];
#pragma unroll
      for (int mi = 0; mi < 2; mi++)
        pf[mi] = *(const bf16x8*)&Ps[wave][(mi * 16 + l15) * 80 + k0 * 32 + quad * 8];
      __builtin_amdgcn_s_setprio(1);
#pragma unroll
      for (int nj = 0; nj < 8; nj++) {
        bf16x8 vf = *(const bf16x8*)&Vt32[(nj * 16 + l15) * 44 + k0 * 16 + quad * 4];
#pragma unroll
        for (int mi = 0; mi < 2; mi++)
          oa[mi][nj] = __builtin_amdgcn_mfma_f32_16x16x32_bf16(pf[mi], vf, oa[mi][nj], 0, 0, 0);
      }
      __builtin_amdgcn_s_setprio(0);
    }
  }

#pragma unroll
  for (int mi = 0; mi < 2; mi++) {
#pragma unroll
    for (int r = 0; r < 4; r++) {
      int row = wave * 32 + mi * 16 + quad * 4 + r;
      float inv = 1.f / lrow[mi][r];
      u16* op = o + ((size_t)bl * T_SEQ + row) * C_DIM + hh * DHEAD + l15;
#pragma unroll
      for (int nj = 0; nj < 8; nj++)
        op[nj * 16] = f2bf(oa[mi][nj][r] * inv);
    }
  }
}

// ---------------- NormalHead ---------------------------------------------------------
__global__ void head_kernel(const float* __restrict__ x1,
                            const float* __restrict__ bn1g, const float* __restrict__ bn1b,
                            const float* __restrict__ bn1rm, const float* __restrict__ bn1rv,
                            const float* __restrict__ c2W, const float* __restrict__ c2b,
                            const float* __restrict__ bn2g, const float* __restrict__ bn2b,
                            const float* __restrict__ bn2rm, const float* __restrict__ bn2rv,
                            const float* __restrict__ c3W, const float* __restrict__ c3b,
                            float* __restrict__ d1a, float* __restrict__ d2a, float* __restrict__ sca) {
  int r = blockIdx.x * 256 + threadIdx.x;
  if (r >= BN_TOT * T_SEQ) return;
  const float* xp = x1 + (size_t)r * 32;
  float y[32];
  float d1 = 0.f;
#pragma unroll
  for (int oc = 0; oc < 32; oc++) {
    float v = xp[oc];
    float dm = v - bn1rm[oc];
    d1 += dm * dm / bn1rv[oc];
    float t = dm * rsqrtf(bn1rv[oc] + EPS) * bn1g[oc] + bn1b[oc];
    y[oc] = fmaxf(t, 0.f);
  }
  float d2 = 0.f, sacc = 0.f;
#pragma unroll
  for (int o2 = 0; o2 < 16; o2++) {
    float s2 = 0.f;
#pragma unroll
    for (int oc = 0; oc < 32; oc++) s2 = fmaf(y[oc], c2W[o2 * 32 + oc], s2);
    s2 += c2b[o2];
    float dm = s2 - bn2rm[o2];
    d2 += dm * dm / bn2rv[o2];
    float t = dm * rsqrtf(bn2rv[o2] + EPS) * bn2g[o2] + bn2b[o2];
    t = fmaxf(t, 0.f);
    sacc = fmaf(t, c3W[o2], sacc);
  }
  float sc = 1.f / (1.f + expf(-(sacc + c3b[0])));
  d1a[r] = sqrtf(d1);
  d2a[r] = sqrtf(d2);
  sca[r] = sc;
}

__global__ void reduce_kernel(const float* __restrict__ d1a, const float* __restrict__ d2a,
                              const float* __restrict__ sca, float* __restrict__ out) {
  int idx = blockIdx.x * 256 + threadIdx.x;
  if (idx >= 32 * T_SEQ) return;
  int b = idx >> 8, t = idx & 255;
  float s1 = 0.f, s2 = 0.f, ss = 0.f;
  for (int n = 0; n < 10; n++) {
    int r = (b * 10 + n) * T_SEQ + t;
    s1 += d1a[r];
    s2 += d2a[r];
    ss += sca[r];
  }
  out[idx] = (s1 + s2) * ss * 0.01f;
}

extern "C" void kernel_launch(void* const* d_in, const int* in_sizes, int n_in,
                              void* d_out, int out_size, void* d_ws, size_t ws_size,
                              hipStream_t stream) {
  const float* x     = (const float*)d_in[0];
  const float* Wemb  = (const float*)d_in[1];
  const float* bemb  = (const float*)d_in[2];
  const float* ln1g  = (const float*)d_in[3];
  const float* ln1b  = (const float*)d_in[4];
  const float* Wqkv  = (const float*)d_in[5];
  const float* Wo    = (const float*)d_in[6];
  const float* bo    = (const float*)d_in[7];
  const float* ln2g  = (const float*)d_in[8];
  const float* ln2b  = (const float*)d_in[9];
  const float* W1    = (const float*)d_in[10];
  const float* b1    = (const float*)d_in[11];
  const float* W2    = (const float*)d_in[12];
  const float* b2    = (const float*)d_in[13];
  const float* c1W   = (const float*)d_in[14];
  const float* c1b   = (const float*)d_in[15];
  const float* bn1g  = (const float*)d_in[16];
  const float* bn1b  = (const float*)d_in[17];
  const float* bn1rm = (const float*)d_in[18];
  const float* bn1rv = (const float*)d_in[19];
  const float* c2W   = (const float*)d_in[20];
  const float* c2b   = (const float*)d_in[21];
  const float* bn2g  = (const float*)d_in[22];
  const float* bn2b  = (const float*)d_in[23];
  const float* bn2rm = (const float*)d_in[24];
  const float* bn2rv = (const float*)d_in[25];
  const float* c3W   = (const float*)d_in[26];
  const float* c3b   = (const float*)d_in[27];

  char* w = (char*)d_ws;
  size_t off = 0;
  auto alloc = [&](size_t nbytes) {
    void* p = (void*)(w + off);
    off += (nbytes + 255) & ~(size_t)255;
    return p;
  };
  float* h      = (float*)alloc((size_t)BN_TOT * T_SEQ * C_DIM * 4);   // 168 MB
  u16*   u_bf   = (u16*)  alloc((size_t)BN_TOT * T_SEQ * C_DIM * 2);   // 84 MB
  u16*   scratch= (u16*)  alloc((size_t)BN_TOT * T_SEQ * QKV_N * 2);   // 252 MB: xpad / qkv / mlp-mid
  u16*   Wct    = (u16*)  alloc((size_t)3 * C_DIM * D_DIM * 2);
  u16*   Wqkvt  = (u16*)  alloc((size_t)2 * QKV_N * C_DIM * 2);
  u16*   Wot    = (u16*)  alloc((size_t)2 * C_DIM * C_DIM * 2);
  u16*   W1t    = (u16*)  alloc((size_t)2 * C_DIM * C_DIM * 2);
  u16*   W2t    = (u16*)  alloc((size_t)2 * C_DIM * C_DIM * 2);
  float* Wc1t   = (float*)alloc((size_t)C_DIM * 32 * 4);
  float* x1     = (float*)alloc((size_t)BN_TOT * T_SEQ * 32 * 4);
  float* d1a    = (float*)alloc((size_t)BN_TOT * T_SEQ * 4);
  float* d2a    = (float*)alloc((size_t)BN_TOT * T_SEQ * 4);
  float* sca    = (float*)alloc((size_t)BN_TOT * T_SEQ * 4);
  u16* xpad  = scratch;   // 169 MB, dead after conv
  u16* qkvbf = scratch;   // 252 MB, per layer
  u16* midbf = scratch;   // 84 MB mlp mid (qkv dead by then)

  {
    size_t nx4 = (size_t)BN_TOT * 258 * 1024 / 4;
    convert_x<<<(unsigned)((nx4 + 255) / 256), 256, 0, stream>>>(x, xpad);
  }
  prep_wct<<<(3 * C_DIM * D_DIM + 255) / 256, 256, 0, stream>>>(Wemb, Wct);
  for (int l = 0; l < 2; ++l) {
    transpose_w<<<dim3(QKV_N / 32, C_DIM / 32), 256, 0, stream>>>(
        Wqkv + (size_t)l * C_DIM * QKV_N, Wqkvt + (size_t)l * QKV_N * C_DIM, C_DIM, QKV_N);
    transpose_w<<<dim3(C_DIM / 32, C_DIM / 32), 256, 0, stream>>>(
        Wo + (size_t)l * C_DIM * C_DIM, Wot + (size_t)l * C_DIM * C_DIM, C_DIM, C_DIM);
    transpose_w<<<dim3(C_DIM / 32, C_DIM / 32), 256, 0, stream>>>(
        W1 + (size_t)l * C_DIM * C_DIM, W1t + (size_t)l * C_DIM * C_DIM, C_DIM, C_DIM);
    transpose_w<<<dim3(C_DIM / 32, C_DIM / 32), 256, 0, stream>>>(
        W2 + (size_t)l * C_DIM * C_DIM, W2t + (size_t)l * C_DIM * C_DIM, C_DIM, C_DIM);
  }
  prep_c1t<<<(C_DIM * 32 + 255) / 256, 256, 0, stream>>>(c1W, Wc1t);

  // conv as 3 shifted GEMMs over padded bf16 x, relu+bias -> h fp32
  gemm_mfma<3, 3><<<dim3(C_DIM / 128, 2, BN_TOT), 256, 0, stream>>>(
      xpad, 1024, 258, Wct, (size_t)C_DIM * D_DIM, D_DIM, h, nullptr, bemb, C_DIM, 256);

  for (int l = 0; l < 2; ++l) {
    ln_kernel<<<BN_TOT * T_SEQ / 4, 256, 0, stream>>>(h, ln1g + l * C_DIM, ln1b + l * C_DIM, u_bf);
    gemm_mfma<1, 4><<<dim3(QKV_N / 128, 640, 1), 256, 0, stream>>>(
        u_bf, C_DIM, 0, Wqkvt + (size_t)l * QKV_N * C_DIM, 0, C_DIM,
        nullptr, qkvbf, nullptr, QKV_N, 0);
    attn_mfma<<<dim3(NHEAD, BN_TOT), 512, 0, stream>>>(qkvbf, u_bf);
    gemm_mfma<1, 1><<<dim3(C_DIM / 128, 640, 1), 256, 0, stream>>>(
        u_bf, C_DIM, 0, Wot + (size_t)l * C_DIM * C_DIM, 0, C_DIM, h, nullptr, bo + l * C_DIM, C_DIM, 0);
    ln_kernel<<<BN_TOT * T_SEQ / 4, 256, 0, stream>>>(h, ln2g + l * C_DIM, ln2b + l * C_DIM, u_bf);
    gemm_mfma<1, 2><<<dim3(C_DIM / 128, 640, 1), 256, 0, stream>>>(
        u_bf, C_DIM, 0, W1t + (size_t)l * C_DIM * C_DIM, 0, C_DIM, nullptr, midbf, b1 + l * C_DIM, C_DIM, 0);
    gemm_mfma<1, 1><<<dim3(C_DIM / 128, 640, 1), 256, 0, stream>>>(
        midbf, C_DIM, 0, W2t + (size_t)l * C_DIM * C_DIM, 0, C_DIM, h, nullptr, b2 + l * C_DIM, C_DIM, 0);
  }

  gemm_f32<32, 1><<<dim3(1, 81920 / 64), 256, 0, stream>>>(h, Wc1t, x1, c1b, 81920, 32, C_DIM);
  head_kernel<<<(BN_TOT * T_SEQ + 255) / 256, 256, 0, stream>>>(
      x1, bn1g, bn1b, bn1rm, bn1rv, c2W, c2b, bn2g, bn2b, bn2rm, bn2rv, c3W, c3b, d1a, d2a, sca);
  reduce_kernel<<<32, 256, 0, stream>>>(d1a, d2a, sca, (float*)d_out);
}

// Round 5
// 2326.591 us; speedup vs baseline: 1.2407x; 1.0233x over previous
//
#include <hip/hip_runtime.h>
#include <math.h>

#define T_SEQ 256
#define C_DIM 512
#define D_DIM 1024
#define BN_TOT 320
#define NHEAD 4
#define DHEAD 128
#define QKV_N 1536
#define EPS 1e-5f
#define ATT_SCALE 0.08838834764831845f

typedef unsigned short u16;
typedef unsigned int u32;
typedef __attribute__((ext_vector_type(8))) short bf16x8;
typedef __attribute__((ext_vector_type(4))) float f32x4;

__device__ __forceinline__ u16 f2bf(float f) {
  union { float f; u32 u; } v; v.f = f;
  u32 r = v.u + 0x7fffu + ((v.u >> 16) & 1u);
  return (u16)(r >> 16);
}

__device__ __forceinline__ void gload_lds16(const u16* g, u16* l) {
  __builtin_amdgcn_global_load_lds((const __attribute__((address_space(1))) u32*)g,
                                   (__attribute__((address_space(3))) u32*)l, 16, 0, 0);
}

// ---------------- prep kernels -------------------------------------------------------
__global__ void convert_x(const float* __restrict__ x, u16* __restrict__ xpad) {
  size_t i4 = ((size_t)blockIdx.x * 256 + threadIdx.x) * 4;
  if (i4 >= (size_t)BN_TOT * 258 * 1024) return;
  size_t row = i4 >> 10; int col = (int)(i4 & 1023);
  int bn = (int)(row / 258), tr = (int)(row % 258);
  ushort4 o;
  if (tr == 0 || tr == 257) {
    o.x = 0; o.y = 0; o.z = 0; o.w = 0;
  } else {
    float4 v = *(const float4*)&x[((size_t)bn * 256 + tr - 1) * 1024 + col];
    o.x = f2bf(v.x); o.y = f2bf(v.y); o.z = f2bf(v.z); o.w = f2bf(v.w);
  }
  *(ushort4*)&xpad[i4] = o;
}

__global__ void prep_wct(const float* __restrict__ Wemb, u16* __restrict__ Wct) {
  int idx = blockIdx.x * 256 + threadIdx.x;
  if (idx >= 3 * C_DIM * D_DIM) return;
  int d = idx & 1023;
  int c = (idx >> 10) & 511;
  int s = idx >> 19;
  Wct[idx] = f2bf(Wemb[(c * D_DIM + d) * 3 + s]);
}

// tiled transpose: src [K][N] fp32 -> dst [N][K] bf16. 32x32 tiles, coalesced both sides.
__launch_bounds__(256)
__global__ void transpose_w(const float* __restrict__ src, u16* __restrict__ dst, int K, int N) {
  __shared__ float t[32][33];
  int tid = threadIdx.x;
  int n0 = blockIdx.x * 32, k0 = blockIdx.y * 32;
  int r = tid >> 3, c4 = (tid & 7) * 4;
  float4 v = *(const float4*)&src[(size_t)(k0 + r) * N + n0 + c4];
  t[r][c4 + 0] = v.x; t[r][c4 + 1] = v.y; t[r][c4 + 2] = v.z; t[r][c4 + 3] = v.w;
  __syncthreads();
  ushort4 o;
  o.x = f2bf(t[c4 + 0][r]);
  o.y = f2bf(t[c4 + 1][r]);
  o.z = f2bf(t[c4 + 2][r]);
  o.w = f2bf(t[c4 + 3][r]);
  *(ushort4*)&dst[(size_t)(n0 + r) * K + k0 + c4] = o;
}

__global__ void prep_c1t(const float* __restrict__ c1W, float* __restrict__ Wt) {
  int idx = blockIdx.x * 256 + threadIdx.x;
  if (idx >= C_DIM * 32) return;
  int n = idx & 31;
  int k = idx >> 5;
  Wt[idx] = c1W[n * C_DIM + k];
}

// ---------------- bf16 MFMA GEMM -----------------------------------------------------
// EPI: 0 = store fp32, 1 = C += acc+bias (fp32), 2 = Cbf = bf16(gelu(acc+bias)),
//      3 = C = relu(acc+bias) fp32, 4 = Cbf = bf16(acc)
// T2 LDS swizzle (rule #21): linear gload_lds dest, pre-swizzled global source col,
// matching XOR on ds_read.
// T3-minimum 2-phase pipeline: double-buffered LDS; STAGE(t+1) issued BEFORE
// compute(t); one vmcnt(0)+raw s_barrier per tile.
// Panel-XCD swizzle: HW assigns orig%8 -> XCD. The gx N-block siblings sharing an
// A row-panel are consecutive in orig, so by default they land on DIFFERENT XCDs
// (A-panel fetched from HBM up to gx times). Remap so the XCD selector is the
// row-panel group: all siblings of a panel run on one XCD -> A-panel is an
// L2-hit after the first fetch. Bijective when (gy*gz) % 8 == 0 (all our grids: 640).
template <int S, int EPI>
__launch_bounds__(256)
__global__ void gemm_mfma(const u16* __restrict__ A, int lda, int aRowsPerZ,
                          const u16* __restrict__ Bt, size_t bShift, int K,
                          float* __restrict__ C, u16* __restrict__ Cbf,
                          const float* __restrict__ bias, int N, int cRowsPerZ) {
  __shared__ __align__(16) u16 lds_all[2 * 16384];   // 64 KB: 2 x (A 16KB + B 16KB)
  float (*ldsT)[132] = (float (*)[132])lds_all;      // epilogue alias (33 KB)

  const int tid = threadIdx.x;
  const int lane = tid & 63;
  const int wave = tid >> 6;
  const int wm = wave >> 1, wn = wave & 1;
  const int quad = lane >> 4;
  const int l15 = lane & 15;
  const int srow = lane >> 3;                    // 0..7 within staging group
  const int scol = ((lane & 7) ^ srow) * 8;      // swizzled source col (u16)
  const int xk = (l15 & 7) * 8;                  // read-side XOR (u16)

  unsigned gx = gridDim.x, gy = gridDim.y, gz = gridDim.z;
  unsigned orig = (blockIdx.z * gy + blockIdx.y) * gx + blockIdx.x;
  unsigned P = gy * gz;                          // number of A row-panels
  unsigned bx, by, bz;
  if ((P & 7u) == 0u) {
    unsigned xcd = orig & 7u, slot = orig >> 3;
    bx = slot % gx;
    unsigned panel = xcd * (P >> 3) + slot / gx;
    by = panel % gy;
    bz = panel / gy;
  } else {
    bx = blockIdx.x; by = blockIdx.y; bz = blockIdx.z;
  }

  const int n0 = bx * 128;
  const int arow0 = bz * aRowsPerZ + by * 128;
  const int crow0 = bz * cRowsPerZ + by * 128;

  const int ksteps = K >> 6;
  const int nt = S * ksteps;

  f32x4 acc[4][4] = {};

  auto stage = [&](int buf, int t) {
    int s = (S == 1) ? 0 : (t / ksteps);
    int k0 = (S == 1) ? (t << 6) : ((t - s * ksteps) << 6);
    const u16* Ab = A + ((size_t)arow0 + s) * (size_t)lda + k0;
    const u16* Bb = Bt + (size_t)s * bShift + k0;
    u16* Al = lds_all + buf * 16384;
    u16* Bl = Al + 8192;
#pragma unroll
    for (int c = 0; c < 4; ++c) {
      int chunk = wave * 4 + c;
      gload_lds16(Ab + (size_t)(chunk * 8 + srow) * lda + scol, Al + chunk * 512);
    }
#pragma unroll
    for (int c = 0; c < 4; ++c) {
      int chunk = wave * 4 + c;
      gload_lds16(Bb + (size_t)(n0 + chunk * 8 + srow) * K + scol, Bl + chunk * 512);
    }
  };

  auto compute = [&](int buf) {
    const u16* Al = lds_all + buf * 16384;
    const u16* Bl = Al + 8192;
#pragma unroll
    for (int kk = 0; kk < 64; kk += 32) {
      bf16x8 af[4], bfr[4];
#pragma unroll
      for (int mt = 0; mt < 4; ++mt)
        af[mt] = *(const bf16x8*)&Al[(wm * 64 + mt * 16 + l15) * 64 + ((kk + quad * 8) ^ xk)];
#pragma unroll
      for (int nt2 = 0; nt2 < 4; ++nt2)
        bfr[nt2] = *(const bf16x8*)&Bl[(wn * 64 + nt2 * 16 + l15) * 64 + ((kk + quad * 8) ^ xk)];
#pragma unroll
      for (int mt = 0; mt < 4; ++mt)
#pragma unroll
        for (int nt2 = 0; nt2 < 4; ++nt2)
          acc[mt][nt2] = __builtin_amdgcn_mfma_f32_16x16x32_bf16(af[mt], bfr[nt2], acc[mt][nt2], 0, 0, 0);
    }
  };

  // prologue
  stage(0, 0);
  asm volatile("s_waitcnt vmcnt(0)" ::: "memory");
  __builtin_amdgcn_s_barrier();
  __builtin_amdgcn_sched_barrier(0);

  int cur = 0;
  for (int t = 0; t < nt - 1; ++t) {
    stage(cur ^ 1, t + 1);         // issue next-tile loads (latency hides under compute)
    compute(cur);
    __builtin_amdgcn_sched_barrier(0);
    asm volatile("s_waitcnt vmcnt(0)" ::: "memory");
    __builtin_amdgcn_s_barrier();
    __builtin_amdgcn_sched_barrier(0);
    cur ^= 1;
  }
  compute(cur);                    // last tile, nothing to prefetch

  __syncthreads();                 // full drain before LDS reuse

  // ---- epilogue: transpose acc through LDS, vectorized global IO ----
  const int rgrp = tid >> 5;        // 0..7 (8 rows each)
  const int c4 = (tid & 31) * 4;    // local col, 4-wide
  const int gcol = n0 + c4;
  float4 bias4 = make_float4(0.f, 0.f, 0.f, 0.f);
  if constexpr (EPI == 1 || EPI == 2 || EPI == 3) bias4 = *(const float4*)&bias[gcol];

#pragma unroll
  for (int p = 0; p < 2; ++p) {
    if (wm == p) {
#pragma unroll
      for (int mt = 0; mt < 4; ++mt)
#pragma unroll
        for (int nt2 = 0; nt2 < 4; ++nt2)
#pragma unroll
          for (int r = 0; r < 4; ++r)
            ldsT[mt * 16 + quad * 4 + r][wn * 64 + nt2 * 16 + l15] = acc[mt][nt2][r];
    }
    __syncthreads();
#pragma unroll
    for (int j = 0; j < 8; ++j) {
      int lrow = rgrp * 8 + j;
      size_t grow = (size_t)crow0 + p * 64 + lrow;
      float4 v = *(const float4*)&ldsT[lrow][c4];
      if constexpr (EPI == 0) {
        *(float4*)&C[grow * N + gcol] = v;
      } else if constexpr (EPI == 1) {
        float4 c = *(const float4*)&C[grow * N + gcol];
        c.x += v.x + bias4.x; c.y += v.y + bias4.y;
        c.z += v.z + bias4.z; c.w += v.w + bias4.w;
        *(float4*)&C[grow * N + gcol] = c;
      } else if constexpr (EPI == 2) {
        float t0 = v.x + bias4.x, t1 = v.y + bias4.y, t2 = v.z + bias4.z, t3 = v.w + bias4.w;
        ushort4 o;
        o.x = f2bf(t0 * 0.5f * (1.f + erff(t0 * 0.70710678118f)));
        o.y = f2bf(t1 * 0.5f * (1.f + erff(t1 * 0.70710678118f)));
        o.z = f2bf(t2 * 0.5f * (1.f + erff(t2 * 0.70710678118f)));
        o.w = f2bf(t3 * 0.5f * (1.f + erff(t3 * 0.70710678118f)));
        *(ushort4*)&Cbf[grow * N + gcol] = o;
      } else if constexpr (EPI == 3) {
        float4 c;
        c.x = fmaxf(v.x + bias4.x, 0.f); c.y = fmaxf(v.y + bias4.y, 0.f);
        c.z = fmaxf(v.z + bias4.z, 0.f); c.w = fmaxf(v.w + bias4.w, 0.f);
        *(float4*)&C[grow * N + gcol] = c;
      } else {
        ushort4 o;
        o.x = f2bf(v.x); o.y = f2bf(v.y); o.z = f2bf(v.z); o.w = f2bf(v.w);
        *(ushort4*)&Cbf[grow * N + gcol] = o;
      }
    }
    __syncthreads();
  }
}

// ---------------- small fp32 GEMM (head c1: N=32) ------------------------------------
template <int NT, int EPI>
__launch_bounds__(256)
__global__ void gemm_f32(const float* __restrict__ A, const float* __restrict__ B,
                         float* __restrict__ C, const float* __restrict__ bias,
                         int M, int N, int K) {
  __shared__ __align__(16) float As[16][68];
  __shared__ __align__(16) float Bs[16][NT + 4];
  int tid = threadIdx.x;
  int tx = tid & 15, ty = tid >> 4;
  int n0 = blockIdx.x * NT, m0 = blockIdx.y * 64;
  constexpr int TN = NT / 16;
  float acc[4][TN] = {};
  int arow = tid >> 2, akg = (tid & 3) * 4;
  int bk, bng;
  if (NT == 64) { bk = tid >> 4; bng = (tid & 15) * 4; }
  else          { bk = tid >> 3; bng = (tid & 7) * 4; }
  bool bload = (NT == 64) || (tid < 128);
  const float* Ap = A + (size_t)(m0 + arow) * K + akg;
  const float* Bp = B + (size_t)bk * N + n0 + bng;
  for (int k0 = 0; k0 < K; k0 += 16) {
    float4 av = *(const float4*)(Ap + k0);
    float4 bv = make_float4(0.f, 0.f, 0.f, 0.f);
    if (bload) bv = *(const float4*)(Bp + (size_t)k0 * N);
    __syncthreads();
    As[akg + 0][arow] = av.x; As[akg + 1][arow] = av.y;
    As[akg + 2][arow] = av.z; As[akg + 3][arow] = av.w;
    if (bload) *(float4*)&Bs[bk][bng] = bv;
    __syncthreads();
#pragma unroll
    for (int k = 0; k < 16; ++k) {
      float4 a4 = *(const float4*)&As[k][ty * 4];
      float a[4] = {a4.x, a4.y, a4.z, a4.w};
      float b[TN];
#pragma unroll
      for (int j = 0; j < TN; j++) b[j] = Bs[k][tx * TN + j];
#pragma unroll
      for (int i = 0; i < 4; i++)
#pragma unroll
        for (int j = 0; j < TN; j++) acc[i][j] = fmaf(a[i], b[j], acc[i][j]);
    }
  }
#pragma unroll
  for (int i = 0; i < 4; i++) {
    size_t row = m0 + ty * 4 + i;
    float* Cp = C + row * (size_t)N + n0 + tx * TN;
#pragma unroll
    for (int j = 0; j < TN; j++) {
      float v = acc[i][j];
      if (EPI >= 1) v += bias[n0 + tx * TN + j];
      Cp[j] = v;
    }
  }
}

// ---------------- LayerNorm over last dim (512), bf16 out ----------------------------
__launch_bounds__(256)
__global__ void ln_kernel(const float* __restrict__ h, const float* __restrict__ g,
                          const float* __restrict__ b, u16* __restrict__ u) {
  int row = blockIdx.x * 4 + (threadIdx.x >> 6);
  int lane = threadIdx.x & 63;
  const float* hp = h + (size_t)row * C_DIM + lane * 8;
  float4 a0 = *(const float4*)hp;
  float4 a1 = *(const float4*)(hp + 4);
  float s = a0.x + a0.y + a0.z + a0.w + a1.x + a1.y + a1.z + a1.w;
#pragma unroll
  for (int o = 32; o > 0; o >>= 1) s += __shfl_xor(s, o);
  float mu = s * (1.f / 512.f);
  float d[8] = {a0.x - mu, a0.y - mu, a0.z - mu, a0.w - mu,
                a1.x - mu, a1.y - mu, a1.z - mu, a1.w - mu};
  float q = 0.f;
#pragma unroll
  for (int j = 0; j < 8; ++j) q += d[j] * d[j];
#pragma unroll
  for (int o = 32; o > 0; o >>= 1) q += __shfl_xor(q, o);
  float rs = rsqrtf(q * (1.f / 512.f) + EPS);
  const float* gp = g + lane * 8;
  const float* bp = b + lane * 8;
  float4 g0 = *(const float4*)gp, g1 = *(const float4*)(gp + 4);
  float4 b0 = *(const float4*)bp, b1 = *(const float4*)(bp + 4);
  float gv[8] = {g0.x, g0.y, g0.z, g0.w, g1.x, g1.y, g1.z, g1.w};
  float bv[8] = {b0.x, b0.y, b0.z, b0.w, b1.x, b1.y, b1.z, b1.w};
  ushort4 o0, o1;
  o0.x = f2bf(d[0] * rs * gv[0] + bv[0]);
  o0.y = f2bf(d[1] * rs * gv[1] + bv[1]);
  o0.z = f2bf(d[2] * rs * gv[2] + bv[2]);
  o0.w = f2bf(d[3] * rs * gv[3] + bv[3]);
  o1.x = f2bf(d[4] * rs * gv[4] + bv[4]);
  o1.y = f2bf(d[5] * rs * gv[5] + bv[5]);
  o1.z = f2bf(d[6] * rs * gv[6] + bv[6]);
  o1.w = f2bf(d[7] * rs * gv[7] + bv[7]);
  u16* up = u + (size_t)row * C_DIM + lane * 8;
  *(ushort4*)up = o0;
  *(ushort4*)(up + 4) = o1;
}

// ---------------- MFMA flash attention: block = (head, bn), 8 waves ------------------
// Panel-XCD swizzle: 4 head-blocks share one bl's K/V panel -> keep them on one XCD.
__launch_bounds__(512, 2)
__global__ void attn_mfma(const u16* __restrict__ qkv, u16* __restrict__ o) {
  __shared__ u16 Ks[64 * 136];        // [kk][d], pad 136
  __shared__ u32 Vt32[128 * 44];      // [d][kk-pair], pad 44 dwords (=88 u16)
  __shared__ u16 Ps[8][32 * 80];      // per-wave P [m][kk], pad 80

  const int tid = threadIdx.x;
  const int lane = tid & 63, wave = tid >> 6;
  const int quad = lane >> 4, l15 = lane & 15;
  unsigned orig = blockIdx.y * 4 + blockIdx.x;   // gx = NHEAD = 4, gy = 320
  unsigned xcd = orig & 7u, slot = orig >> 3;
  const int hh = slot & 3;
  const int bl = xcd * 40 + (slot >> 2);         // 320/8 = 40 panels per XCD
  const u16* base = qkv + (size_t)bl * T_SEQ * QKV_N;

  bf16x8 qf[2][4];
#pragma unroll
  for (int mi = 0; mi < 2; mi++) {
    int row = wave * 32 + mi * 16 + l15;
    const u16* qp = base + (size_t)row * QKV_N + hh * DHEAD + quad * 8;
#pragma unroll
    for (int k0 = 0; k0 < 4; k0++)
      qf[mi][k0] = *(const bf16x8*)(qp + k0 * 32);
  }

  f32x4 oa[2][8] = {};
  float mrow[2][4], lrow[2][4];
#pragma unroll
  for (int mi = 0; mi < 2; mi++)
#pragma unroll
    for (int r = 0; r < 4; r++) { mrow[mi][r] = -1e30f; lrow[mi][r] = 0.f; }

  for (int kt = 0; kt < 4; kt++) {
    __syncthreads();
    {
      int kk = tid >> 3, dbase = (tid & 7) * 16;
      const u16* kp = base + (size_t)(kt * 64 + kk) * QKV_N + C_DIM + hh * DHEAD + dbase;
      uint4 a = *(const uint4*)kp;
      uint4 b = *(const uint4*)(kp + 8);
      *(uint4*)&Ks[kk * 136 + dbase] = a;
      *(uint4*)&Ks[kk * 136 + dbase + 8] = b;
    }
    {
      int kkp = tid >> 4, dbase = (tid & 15) * 8;
      const u16* vp = base + (size_t)(kt * 64 + kkp * 2) * QKV_N + 2 * C_DIM + hh * DHEAD + dbase;
      union { uint4 u; u16 h[8]; } va, vb;
      va.u = *(const uint4*)vp;
      vb.u = *(const uint4*)(vp + QKV_N);
#pragma unroll
      for (int j = 0; j < 8; j++)
        Vt32[(dbase + j) * 44 + kkp] = (u32)va.h[j] | ((u32)vb.h[j] << 16);
    }
    __syncthreads();

    f32x4 sa[2][4] = {};
#pragma unroll
    for (int k0 = 0; k0 < 4; k0++) {
      bf16x8 kf[4];
#pragma unroll
      for (int ni = 0; ni < 4; ni++)
        kf[ni] = *(const bf16x8*)&Ks[(ni * 16 + l15) * 136 + k0 * 32 + quad * 8];
      __builtin_amdgcn_s_setprio(1);
#pragma unroll
      for (int mi = 0; mi < 2; mi++)
#pragma unroll
        for (int ni = 0; ni < 4; ni++)
          sa[mi][ni] = __builtin_amdgcn_mfma_f32_16x16x32_bf16(qf[mi][k0], kf[ni], sa[mi][ni], 0, 0, 0);
      __builtin_amdgcn_s_setprio(0);
    }

#pragma unroll
    for (int mi = 0; mi < 2; mi++) {
#pragma unroll
      for (int r = 0; r < 4; r++) {
        float mx = fmaxf(fmaxf(sa[mi][0][r], sa[mi][1][r]), fmaxf(sa[mi][2][r], sa[mi][3][r]));
        mx = fmaxf(mx, __shfl_xor(mx, 1));
        mx = fmaxf(mx, __shfl_xor(mx, 2));
        mx = fmaxf(mx, __shfl_xor(mx, 4));
        mx = fmaxf(mx, __shfl_xor(mx, 8));
        mx *= ATT_SCALE;
        float mnew = fmaxf(mrow[mi][r], mx);
        float alpha = __expf(mrow[mi][r] - mnew);
        mrow[mi][r] = mnew;
        float rs = 0.f;
#pragma unroll
        for (int ni = 0; ni < 4; ni++) {
          float p = __expf(sa[mi][ni][r] * ATT_SCALE - mnew);
          rs += p;
          Ps[wave][(mi * 16 + quad * 4 + r) * 80 + ni * 16 + l15] = f2bf(p);
        }
        rs += __shfl_xor(rs, 1);
        rs += __shfl_xor(rs, 2);
        rs += __shfl_xor(rs, 4);
        rs += __shfl_xor(rs, 8);
        lrow[mi][r] = lrow[mi][r] * alpha + rs;
#pragma unroll
        for (int nj = 0; nj < 8; nj++) oa[mi][nj][r] *= alpha;
      }
    }

#pragma unroll
    for (int k0 = 0; k0 < 2; k0++) {
      bf16x8 pf[2];
#pragma unroll
      for (int mi = 0; mi < 2; mi++)
        pf[mi] = *(const bf16x8*)&Ps[wave][(mi * 16 + l15) * 80 + k0 * 32 + quad * 8];
      __builtin_amdgcn_s_setprio(1);
#pragma unroll
      for (int nj = 0; nj < 8; nj++) {
        bf16x8 vf = *(const bf16x8*)&Vt32[(nj * 16 + l15) * 44 + k0 * 16 + quad * 4];
#pragma unroll
        for (int mi = 0; mi < 2; mi++)
          oa[mi][nj] = __builtin_amdgcn_mfma_f32_16x16x32_bf16(pf[mi], vf, oa[mi][nj], 0, 0, 0);
      }
      __builtin_amdgcn_s_setprio(0);
    }
  }

#pragma unroll
  for (int mi = 0; mi < 2; mi++) {
#pragma unroll
    for (int r = 0; r < 4; r++) {
      int row = wave * 32 + mi * 16 + quad * 4 + r;
      float inv = 1.f / lrow[mi][r];
      u16* op = o + ((size_t)bl * T_SEQ + row) * C_DIM + hh * DHEAD + l15;
#pragma unroll
      for (int nj = 0; nj < 8; nj++)
        op[nj * 16] = f2bf(oa[mi][nj][r] * inv);
    }
  }
}

// ---------------- NormalHead ---------------------------------------------------------
__global__ void head_kernel(const float* __restrict__ x1,
                            const float* __restrict__ bn1g, const float* __restrict__ bn1b,
                            const float* __restrict__ bn1rm, const float* __restrict__ bn1rv,
                            const float* __restrict__ c2W, const float* __restrict__ c2b,
                            const float* __restrict__ bn2g, const float* __restrict__ bn2b,
                            const float* __restrict__ bn2rm, const float* __restrict__ bn2rv,
                            const float* __restrict__ c3W, const float* __restrict__ c3b,
                            float* __restrict__ d1a, float* __restrict__ d2a, float* __restrict__ sca) {
  int r = blockIdx.x * 256 + threadIdx.x;
  if (r >= BN_TOT * T_SEQ) return;
  const float* xp = x1 + (size_t)r * 32;
  float y[32];
  float d1 = 0.f;
#pragma unroll
  for (int oc = 0; oc < 32; oc++) {
    float v = xp[oc];
    float dm = v - bn1rm[oc];
    d1 += dm * dm / bn1rv[oc];
    float t = dm * rsqrtf(bn1rv[oc] + EPS) * bn1g[oc] + bn1b[oc];
    y[oc] = fmaxf(t, 0.f);
  }
  float d2 = 0.f, sacc = 0.f;
#pragma unroll
  for (int o2 = 0; o2 < 16; o2++) {
    float s2 = 0.f;
#pragma unroll
    for (int oc = 0; oc < 32; oc++) s2 = fmaf(y[oc], c2W[o2 * 32 + oc], s2);
    s2 += c2b[o2];
    float dm = s2 - bn2rm[o2];
    d2 += dm * dm / bn2rv[o2];
    float t = dm * rsqrtf(bn2rv[o2] + EPS) * bn2g[o2] + bn2b[o2];
    t = fmaxf(t, 0.f);
    sacc = fmaf(t, c3W[o2], sacc);
  }
  float sc = 1.f / (1.f + expf(-(sacc + c3b[0])));
  d1a[r] = sqrtf(d1);
  d2a[r] = sqrtf(d2);
  sca[r] = sc;
}

__global__ void reduce_kernel(const float* __restrict__ d1a, const float* __restrict__ d2a,
                              const float* __restrict__ sca, float* __restrict__ out) {
  int idx = blockIdx.x * 256 + threadIdx.x;
  if (idx >= 32 * T_SEQ) return;
  int b = idx >> 8, t = idx & 255;
  float s1 = 0.f, s2 = 0.f, ss = 0.f;
  for (int n = 0; n < 10; n++) {
    int r = (b * 10 + n) * T_SEQ + t;
    s1 += d1a[r];
    s2 += d2a[r];
    ss += sca[r];
  }
  out[idx] = (s1 + s2) * ss * 0.01f;
}

extern "C" void kernel_launch(void* const* d_in, const int* in_sizes, int n_in,
                              void* d_out, int out_size, void* d_ws, size_t ws_size,
                              hipStream_t stream) {
  const float* x     = (const float*)d_in[0];
  const float* Wemb  = (const float*)d_in[1];
  const float* bemb  = (const float*)d_in[2];
  const float* ln1g  = (const float*)d_in[3];
  const float* ln1b  = (const float*)d_in[4];
  const float* Wqkv  = (const float*)d_in[5];
  const float* Wo    = (const float*)d_in[6];
  const float* bo    = (const float*)d_in[7];
  const float* ln2g  = (const float*)d_in[8];
  const float* ln2b  = (const float*)d_in[9];
  const float* W1    = (const float*)d_in[10];
  const float* b1    = (const float*)d_in[11];
  const float* W2    = (const float*)d_in[12];
  const float* b2    = (const float*)d_in[13];
  const float* c1W   = (const float*)d_in[14];
  const float* c1b   = (const float*)d_in[15];
  const float* bn1g  = (const float*)d_in[16];
  const float* bn1b  = (const float*)d_in[17];
  const float* bn1rm = (const float*)d_in[18];
  const float* bn1rv = (const float*)d_in[19];
  const float* c2W   = (const float*)d_in[20];
  const float* c2b   = (const float*)d_in[21];
  const float* bn2g  = (const float*)d_in[22];
  const float* bn2b  = (const float*)d_in[23];
  const float* bn2rm = (const float*)d_in[24];
  const float* bn2rv = (const float*)d_in[25];
  const float* c3W   = (const float*)d_in[26];
  const float* c3b   = (const float*)d_in[27];

  char* w = (char*)d_ws;
  size_t off = 0;
  auto alloc = [&](size_t nbytes) {
    void* p = (void*)(w + off);
    off += (nbytes + 255) & ~(size_t)255;
    return p;
  };
  float* h      = (float*)alloc((size_t)BN_TOT * T_SEQ * C_DIM * 4);   // 168 MB
  u16*   u_bf   = (u16*)  alloc((size_t)BN_TOT * T_SEQ * C_DIM * 2);   // 84 MB
  u16*   scratch= (u16*)  alloc((size_t)BN_TOT * T_SEQ * QKV_N * 2);   // 252 MB: xpad / qkv / mlp-mid
  u16*   Wct    = (u16*)  alloc((size_t)3 * C_DIM * D_DIM * 2);
  u16*   Wqkvt  = (u16*)  alloc((size_t)2 * QKV_N * C_DIM * 2);
  u16*   Wot    = (u16*)  alloc((size_t)2 * C_DIM * C_DIM * 2);
  u16*   W1t    = (u16*)  alloc((size_t)2 * C_DIM * C_DIM * 2);
  u16*   W2t    = (u16*)  alloc((size_t)2 * C_DIM * C_DIM * 2);
  float* Wc1t   = (float*)alloc((size_t)C_DIM * 32 * 4);
  float* x1     = (float*)alloc((size_t)BN_TOT * T_SEQ * 32 * 4);
  float* d1a    = (float*)alloc((size_t)BN_TOT * T_SEQ * 4);
  float* d2a    = (float*)alloc((size_t)BN_TOT * T_SEQ * 4);
  float* sca    = (float*)alloc((size_t)BN_TOT * T_SEQ * 4);
  u16* xpad  = scratch;   // 169 MB, dead after conv
  u16* qkvbf = scratch;   // 252 MB, per layer
  u16* midbf = scratch;   // 84 MB mlp mid (qkv dead by then)

  {
    size_t nx4 = (size_t)BN_TOT * 258 * 1024 / 4;
    convert_x<<<(unsigned)((nx4 + 255) / 256), 256, 0, stream>>>(x, xpad);
  }
  prep_wct<<<(3 * C_DIM * D_DIM + 255) / 256, 256, 0, stream>>>(Wemb, Wct);
  for (int l = 0; l < 2; ++l) {
    transpose_w<<<dim3(QKV_N / 32, C_DIM / 32), 256, 0, stream>>>(
        Wqkv + (size_t)l * C_DIM * QKV_N, Wqkvt + (size_t)l * QKV_N * C_DIM, C_DIM, QKV_N);
    transpose_w<<<dim3(C_DIM / 32, C_DIM / 32), 256, 0, stream>>>(
        Wo + (size_t)l * C_DIM * C_DIM, Wot + (size_t)l * C_DIM * C_DIM, C_DIM, C_DIM);
    transpose_w<<<dim3(C_DIM / 32, C_DIM / 32), 256, 0, stream>>>(
        W1 + (size_t)l * C_DIM * C_DIM, W1t + (size_t)l * C_DIM * C_DIM, C_DIM, C_DIM);
    transpose_w<<<dim3(C_DIM / 32, C_DIM / 32), 256, 0, stream>>>(
        W2 + (size_t)l * C_DIM * C_DIM, W2t + (size_t)l * C_DIM * C_DIM, C_DIM, C_DIM);
  }
  prep_c1t<<<(C_DIM * 32 + 255) / 256, 256, 0, stream>>>(c1W, Wc1t);

  // conv as 3 shifted GEMMs over padded bf16 x, relu+bias -> h fp32
  gemm_mfma<3, 3><<<dim3(C_DIM / 128, 2, BN_TOT), 256, 0, stream>>>(
      xpad, 1024, 258, Wct, (size_t)C_DIM * D_DIM, D_DIM, h, nullptr, bemb, C_DIM, 256);

  for (int l = 0; l < 2; ++l) {
    ln_kernel<<<BN_TOT * T_SEQ / 4, 256, 0, stream>>>(h, ln1g + l * C_DIM, ln1b + l * C_DIM, u_bf);
    gemm_mfma<1, 4><<<dim3(QKV_N / 128, 640, 1), 256, 0, stream>>>(
        u_bf, C_DIM, 0, Wqkvt + (size_t)l * QKV_N * C_DIM, 0, C_DIM,
        nullptr, qkvbf, nullptr, QKV_N, 0);
    attn_mfma<<<dim3(NHEAD, BN_TOT), 512, 0, stream>>>(qkvbf, u_bf);
    gemm_mfma<1, 1><<<dim3(C_DIM / 128, 640, 1), 256, 0, stream>>>(
        u_bf, C_DIM, 0, Wot + (size_t)l * C_DIM * C_DIM, 0, C_DIM, h, nullptr, bo + l * C_DIM, C_DIM, 0);
    ln_kernel<<<BN_TOT * T_SEQ / 4, 256, 0, stream>>>(h, ln2g + l * C_DIM, ln2b + l * C_DIM, u_bf);
    gemm_mfma<1, 2><<<dim3(C_DIM / 128, 640, 1), 256, 0, stream>>>(
        u_bf, C_DIM, 0, W1t + (size_t)l * C_DIM * C_DIM, 0, C_DIM, nullptr, midbf, b1 + l * C_DIM, C_DIM, 0);
    gemm_mfma<1, 1><<<dim3(C_DIM / 128, 640, 1), 256, 0, stream>>>(
        midbf, C_DIM, 0, W2t + (size_t)l * C_DIM * C_DIM, 0, C_DIM, h, nullptr, b2 + l * C_DIM, C_DIM, 0);
  }

  gemm_f32<32, 1><<<dim3(1, 81920 / 64), 256, 0, stream>>>(h, Wc1t, x1, c1b, 81920, 32, C_DIM);
  head_kernel<<<(BN_TOT * T_SEQ + 255) / 256, 256, 0, stream>>>(
      x1, bn1g, bn1b, bn1rm, bn1rv, c2W, c2b, bn2g, bn2b, bn2rm, bn2rv, c3W, c3b, d1a, d2a, sca);
  reduce_kernel<<<32, 256, 0, stream>>>(d1a, d2a, sca, (float*)d_out);
}